// Round 1
// baseline (16237.045 us; speedup 1.0000x reference)
//
#include <hip/hip_runtime.h>
#include <hip/hip_bf16.h>

#define N_NODES 50000
#define N_EDGES 800000
#define NODE_DIM 256
#define EDGE_DIM 64
#define NUM_REL 4
#define HID 512
#define LAST 128
#define BATCH 16384
#define EPS 1e-10f

// ---------------- scatter kernels ----------------
// one wave (64 lanes) per edge; 4 edges per 256-thread block
__global__ __launch_bounds__(256) void scatter1(
    const float* __restrict__ x, const float* __restrict__ ef,
    const int* __restrict__ esrc, const int* __restrict__ edst, const int* __restrict__ erel,
    float* __restrict__ segX, float* __restrict__ segEF, float* __restrict__ cnt)
{
    int e = blockIdx.x * 4 + (threadIdx.x >> 6);
    if (e >= N_EDGES) return;
    int lane = threadIdx.x & 63;
    int src = esrc[e];
    int seg = edst[e] * NUM_REL + erel[e];
    // node feature part: 256 floats, 4 per lane
    float4 v = *(const float4*)(x + (size_t)src * NODE_DIM + lane * 4);
    float* dst = segX + (size_t)seg * NODE_DIM + lane * 4;
    atomicAdd(dst + 0, v.x);
    atomicAdd(dst + 1, v.y);
    atomicAdd(dst + 2, v.z);
    atomicAdd(dst + 3, v.w);
    // edge feature part: 64 floats, 1 per lane
    atomicAdd(segEF + (size_t)seg * EDGE_DIM + lane, ef[(size_t)e * EDGE_DIM + lane]);
    if (lane == 0) atomicAdd(cnt + seg, 1.0f);
}

__global__ __launch_bounds__(256) void scatter2(
    const float* __restrict__ h1,
    const int* __restrict__ esrc, const int* __restrict__ edst, const int* __restrict__ erel,
    float* __restrict__ segX)
{
    int e = blockIdx.x * 4 + (threadIdx.x >> 6);
    if (e >= N_EDGES) return;
    int lane = threadIdx.x & 63;
    int src = esrc[e];
    int seg = edst[e] * NUM_REL + erel[e];
    const float4* sp = (const float4*)(h1 + (size_t)src * HID) + lane * 2;
    float4 a = sp[0];
    float4 b = sp[1];
    float* dp = segX + (size_t)seg * HID + lane * 8;
    atomicAdd(dp + 0, a.x); atomicAdd(dp + 1, a.y); atomicAdd(dp + 2, a.z); atomicAdd(dp + 3, a.w);
    atomicAdd(dp + 4, b.x); atomicAdd(dp + 5, b.y); atomicAdd(dp + 6, b.z); atomicAdd(dp + 7, b.w);
}

// ---------------- finalize: segX = (segX + cnt*be) / (cnt + eps), in place --------
// one float4 per thread; total4 = N_NODES*NUM_REL*D/4, D = 1<<dlog2
__global__ __launch_bounds__(256) void finalize_seg(
    float* __restrict__ segX, const float* __restrict__ cnt, const float* __restrict__ be,
    int dlog2)
{
    size_t i = (size_t)blockIdx.x * 256 + threadIdx.x;
    size_t base = i * 4;
    int D = 1 << dlog2;
    int s = (int)(base >> dlog2);
    int c = (int)(base & (D - 1));
    float ct = cnt[s];
    float inv = 1.0f / (ct + EPS);
    float4 v = ((float4*)segX)[i];
    float4 b = *(const float4*)(be + c);
    v.x = (v.x + ct * b.x) * inv;
    v.y = (v.y + ct * b.y) * inv;
    v.z = (v.z + ct * b.z) * inv;
    v.w = (v.w + ct * b.w) * inv;
    ((float4*)segX)[i] = v;
}

// ---------------- generic fp32 GEMM: C = act(A @ W^T + bias [+ C_in]) -------------
// A [M,K] row-major (lda=K), W [N,K] row-major, C [M,ldc]; N%64==0, K%16==0
#define BM 64
#define BN 64
#define BK 16

template<int RELU, int ACC>
__global__ __launch_bounds__(256) void gemm_nt(
    const float* __restrict__ A, const float* __restrict__ W,
    float* __restrict__ C, const float* __restrict__ bias,
    int M, int N, int K, int ldc)
{
    __shared__ float As[BK][BM + 4];
    __shared__ float Ws[BK][BN + 4];
    int row0 = blockIdx.x * BM;
    int col0 = blockIdx.y * BN;
    int tid = threadIdx.x;
    int lr = tid >> 2;          // 0..63
    int lc = (tid & 3) * 4;     // 0,4,8,12
    int ty = tid >> 4, tx = tid & 15;
    float acc[4][4] = {};

    for (int k0 = 0; k0 < K; k0 += BK) {
        int gr = row0 + lr;
        float4 v = make_float4(0.f, 0.f, 0.f, 0.f);
        if (gr < M) v = *(const float4*)(A + (size_t)gr * K + k0 + lc);
        As[lc + 0][lr] = v.x; As[lc + 1][lr] = v.y; As[lc + 2][lr] = v.z; As[lc + 3][lr] = v.w;
        int gc = col0 + lr;
        float4 w = *(const float4*)(W + (size_t)gc * K + k0 + lc);
        Ws[lc + 0][lr] = w.x; Ws[lc + 1][lr] = w.y; Ws[lc + 2][lr] = w.z; Ws[lc + 3][lr] = w.w;
        __syncthreads();
#pragma unroll
        for (int kk = 0; kk < BK; ++kk) {
            float4 av = *(const float4*)&As[kk][ty * 4];
            float4 bv = *(const float4*)&Ws[kk][tx * 4];
            float a[4] = {av.x, av.y, av.z, av.w};
            float b[4] = {bv.x, bv.y, bv.z, bv.w};
#pragma unroll
            for (int i = 0; i < 4; ++i)
#pragma unroll
                for (int j = 0; j < 4; ++j)
                    acc[i][j] += a[i] * b[j];
        }
        __syncthreads();
    }

    int gr0 = row0 + ty * 4;
    int gc0 = col0 + tx * 4;
#pragma unroll
    for (int i = 0; i < 4; ++i) {
        int gr = gr0 + i;
        if (gr >= M) continue;
        float* cp = C + (size_t)gr * ldc + gc0;
#pragma unroll
        for (int j = 0; j < 4; ++j) {
            float v = acc[i][j];
            if (bias) v += bias[gc0 + j];
            if (ACC) v += cp[j];
            if (RELU) v = fmaxf(v, 0.f);
            cp[j] = v;
        }
    }
}

// ---------------- head gather: xcat[:,0:128]=h2[d1], [:,128:256]=h2[d2]; ef_g=ef[ctx]
__global__ __launch_bounds__(256) void gather_head(
    const int* __restrict__ inputs, const float* __restrict__ h2,
    const float* __restrict__ ef, float* __restrict__ xcat, float* __restrict__ ef_g)
{
    int i = blockIdx.x;
    int t = threadIdx.x;
    int d1 = inputs[i * 3 + 0];
    int d2 = inputs[i * 3 + 1];
    int ctx = inputs[i * 3 + 2];
    if (t < 128) {
        xcat[(size_t)i * 384 + t] = h2[(size_t)d1 * LAST + t];
    } else {
        int c = t - 128;
        xcat[(size_t)i * 384 + 128 + c] = h2[(size_t)d2 * LAST + c];
    }
    if (t < 64) ef_g[(size_t)i * 64 + t] = ef[(size_t)ctx * EDGE_DIM + t];
}

// ---------------- final matvec: out[i] = dot(f2[i], Wf3) + bf3 --------------------
__global__ __launch_bounds__(256) void final_matvec(
    const float* __restrict__ f2, const float* __restrict__ Wf3,
    const float* __restrict__ bf3, float* __restrict__ out, int M)
{
    int row = blockIdx.x * 4 + (threadIdx.x >> 6);
    int lane = threadIdx.x & 63;
    if (row >= M) return;
    float v = f2[(size_t)row * 64 + lane] * Wf3[lane];
#pragma unroll
    for (int off = 32; off > 0; off >>= 1) v += __shfl_down(v, off);
    if (lane == 0) out[row] = v + bf3[0];
}

extern "C" void kernel_launch(void* const* d_in, const int* in_sizes, int n_in,
                              void* d_out, int out_size, void* d_ws, size_t ws_size,
                              hipStream_t stream)
{
    const int*   inputs       = (const int*)  d_in[0];
    const float* node_feature = (const float*)d_in[1];
    const float* edge_feature = (const float*)d_in[2];
    const int*   edge_src     = (const int*)  d_in[3];
    const int*   edge_dst     = (const int*)  d_in[4];
    const int*   edge_rel     = (const int*)  d_in[5];
    const float* We1 = (const float*)d_in[6];
    const float* be1 = (const float*)d_in[7];
    const float* Wl1 = (const float*)d_in[8];
    const float* bl1 = (const float*)d_in[9];
    const float* Ws1 = (const float*)d_in[10];
    const float* bs1 = (const float*)d_in[11];
    const float* We2 = (const float*)d_in[12];
    const float* be2 = (const float*)d_in[13];
    const float* Wl2 = (const float*)d_in[14];
    const float* bl2 = (const float*)d_in[15];
    const float* Ws2 = (const float*)d_in[16];
    const float* bs2 = (const float*)d_in[17];
    const float* Wc1 = (const float*)d_in[18];
    const float* bc1 = (const float*)d_in[19];
    const float* Wc2 = (const float*)d_in[20];
    const float* bc2 = (const float*)d_in[21];
    const float* Wf1 = (const float*)d_in[22];
    const float* bf1 = (const float*)d_in[23];
    const float* Wf2 = (const float*)d_in[24];
    const float* bf2 = (const float*)d_in[25];
    const float* Wf3 = (const float*)d_in[26];
    const float* bf3 = (const float*)d_in[27];
    float* out = (float*)d_out;

    // ---- workspace layout (floats) ----
    float* ws = (float*)d_ws;
    const size_t SEGX1_N = (size_t)N_NODES * NUM_REL * NODE_DIM;  // 51,200,000
    const size_t SEGEF_N = (size_t)N_NODES * NUM_REL * EDGE_DIM;  // 12,800,000
    const size_t CNT_N   = (size_t)N_NODES * NUM_REL;             //    200,000
    const size_t H1_N    = (size_t)N_NODES * HID;                 // 25,600,000
    const size_t SEGX2_N = (size_t)N_NODES * NUM_REL * HID;       // 102,400,000
    const size_t H2_N    = (size_t)N_NODES * LAST;                //  6,400,000

    float* segX1 = ws;
    float* segEF = segX1 + SEGX1_N;
    float* cnt   = segEF + SEGEF_N;
    float* h1    = cnt + CNT_N;
    float* segX2 = h1 + H1_N;
    float* h2    = segX2 + SEGX2_N;
    // head buffers alias the (dead by then) segX1 region
    float* ef_g = segX1;                          // 16384*64
    float* u3   = ef_g + (size_t)BATCH * 64;      // 16384*256
    float* xcat = u3 + (size_t)BATCH * 256;       // 16384*384
    float* f1   = xcat + (size_t)BATCH * 384;     // 16384*128
    float* f2   = f1 + (size_t)BATCH * 128;       // 16384*64

    // ---- zero the accumulators (segX1+segEF+cnt are contiguous) ----
    hipMemsetAsync(segX1, 0, (SEGX1_N + SEGEF_N + CNT_N) * sizeof(float), stream);
    hipMemsetAsync(segX2, 0, SEGX2_N * sizeof(float), stream);

    // ---- layer 1 ----
    scatter1<<<N_EDGES / 4, 256, 0, stream>>>(node_feature, edge_feature,
                                              edge_src, edge_dst, edge_rel,
                                              segX1, segEF, cnt);
    {   // segX1 += segEF @ We1^T   [200000,64] x [256,64]^T
        dim3 g((N_NODES * NUM_REL + BM - 1) / BM, NODE_DIM / BN);
        gemm_nt<0, 1><<<g, 256, 0, stream>>>(segEF, We1, segX1, nullptr,
                                             N_NODES * NUM_REL, NODE_DIM, EDGE_DIM, NODE_DIM);
    }
    finalize_seg<<<(unsigned)(SEGX1_N / 4 / 256), 256, 0, stream>>>(segX1, cnt, be1, 8);
    {   // h1 = upd1 @ Wl1^T + bl1    [50000,1024] x [512,1024]^T
        dim3 g((N_NODES + BM - 1) / BM, HID / BN);
        gemm_nt<0, 0><<<g, 256, 0, stream>>>(segX1, Wl1, h1, bl1,
                                             N_NODES, HID, NUM_REL * NODE_DIM, HID);
        // h1 = relu(x @ Ws1^T + bs1 + h1)
        gemm_nt<1, 1><<<g, 256, 0, stream>>>(node_feature, Ws1, h1, bs1,
                                             N_NODES, HID, NODE_DIM, HID);
    }

    // ---- layer 2 ----
    scatter2<<<N_EDGES / 4, 256, 0, stream>>>(h1, edge_src, edge_dst, edge_rel, segX2);
    {   // segX2 += segEF @ We2^T   [200000,64] x [512,64]^T
        dim3 g((N_NODES * NUM_REL + BM - 1) / BM, HID / BN);
        gemm_nt<0, 1><<<g, 256, 0, stream>>>(segEF, We2, segX2, nullptr,
                                             N_NODES * NUM_REL, HID, EDGE_DIM, HID);
    }
    finalize_seg<<<(unsigned)(SEGX2_N / 4 / 256), 256, 0, stream>>>(segX2, cnt, be2, 9);
    {   // h2 = upd2 @ Wl2^T + bl2    [50000,2048] x [128,2048]^T
        dim3 g((N_NODES + BM - 1) / BM, LAST / BN);
        gemm_nt<0, 0><<<g, 256, 0, stream>>>(segX2, Wl2, h2, bl2,
                                             N_NODES, LAST, NUM_REL * HID, LAST);
        // h2 = relu(h1 @ Ws2^T + bs2 + h2)
        gemm_nt<1, 1><<<g, 256, 0, stream>>>(h1, Ws2, h2, bs2,
                                             N_NODES, LAST, HID, LAST);
    }

    // ---- head ----
    gather_head<<<BATCH, 256, 0, stream>>>(inputs, h2, edge_feature, xcat, ef_g);
    {   // u3 = relu(ef_g @ Wc1^T + bc1)   [16384,64] x [256,64]^T
        dim3 g(BATCH / BM, 256 / BN);
        gemm_nt<1, 0><<<g, 256, 0, stream>>>(ef_g, Wc1, u3, bc1, BATCH, 256, 64, 256);
    }
    {   // xcat[:,256:384] = u3 @ Wc2^T + bc2
        dim3 g(BATCH / BM, LAST / BN);
        gemm_nt<0, 0><<<g, 256, 0, stream>>>(u3, Wc2, xcat + 256, bc2, BATCH, LAST, 256, 384);
    }
    {   // f1 = relu(xcat @ Wf1^T + bf1)   [16384,384] x [128,384]^T
        dim3 g(BATCH / BM, LAST / BN);
        gemm_nt<1, 0><<<g, 256, 0, stream>>>(xcat, Wf1, f1, bf1, BATCH, LAST, 384, LAST);
    }
    {   // f2 = relu(f1 @ Wf2^T + bf2)   [16384,128] x [64,128]^T
        dim3 g(BATCH / BM, 64 / BN);
        gemm_nt<1, 0><<<g, 256, 0, stream>>>(f1, Wf2, f2, bf2, BATCH, 64, LAST, 64);
    }
    final_matvec<<<BATCH / 4, 256, 0, stream>>>(f2, Wf3, bf3, out, BATCH);
}

// Round 2
// 2397.206 us; speedup vs baseline: 6.7733x; 6.7733x over previous
//
#include <hip/hip_runtime.h>
#include <hip/hip_bf16.h>

#define N_NODES 50000
#define N_EDGES 800000
#define NODE_DIM 256
#define EDGE_DIM 64
#define NUM_REL 4
#define HID 512
#define LAST 128
#define BATCH 16384
#define EPS 1e-10f
#define NSEG (N_NODES * NUM_REL)

// ================= CSR build =================
__global__ __launch_bounds__(256) void hist_kernel(
    const int* __restrict__ edst, const int* __restrict__ erel, int* __restrict__ hist)
{
    int e = blockIdx.x * 256 + threadIdx.x;
    if (e >= N_EDGES) return;
    atomicAdd(&hist[edst[e] * NUM_REL + erel[e]], 1);
}

#define SCAN_B 2048  // 256 threads * 8 items
__global__ __launch_bounds__(256) void scan1(
    const int* __restrict__ in, int* __restrict__ out, int* __restrict__ bsum, int n)
{
    __shared__ int sh[256];
    int base = blockIdx.x * SCAN_B + threadIdx.x * 8;
    int v[8]; int s = 0;
#pragma unroll
    for (int i = 0; i < 8; ++i) {
        int idx = base + i;
        v[i] = s;
        s += (idx < n) ? in[idx] : 0;
    }
    sh[threadIdx.x] = s;
    __syncthreads();
    for (int off = 1; off < 256; off <<= 1) {
        int t = (threadIdx.x >= off) ? sh[threadIdx.x - off] : 0;
        __syncthreads();
        sh[threadIdx.x] += t;
        __syncthreads();
    }
    int texcl = (threadIdx.x == 0) ? 0 : sh[threadIdx.x - 1];
#pragma unroll
    for (int i = 0; i < 8; ++i) {
        int idx = base + i;
        if (idx < n) out[idx] = texcl + v[i];
    }
    if (threadIdx.x == 255) bsum[blockIdx.x] = sh[255];
}

__global__ void scan2(int* bsum, int nb)
{
    if (threadIdx.x == 0 && blockIdx.x == 0) {
        int s = 0;
        for (int i = 0; i < nb; ++i) { int t = bsum[i]; bsum[i] = s; s += t; }
    }
}

__global__ __launch_bounds__(256) void scan3(int* __restrict__ out, const int* __restrict__ bsum, int n)
{
    int idx = blockIdx.x * SCAN_B + threadIdx.x * 8;
    int add = bsum[blockIdx.x];
#pragma unroll
    for (int i = 0; i < 8; ++i)
        if (idx + i < n) out[idx + i] += add;
}

__global__ __launch_bounds__(256) void csr_fill(
    const int* __restrict__ edst, const int* __restrict__ erel,
    const int* __restrict__ offs, int* __restrict__ cursor, int* __restrict__ csre)
{
    int e = blockIdx.x * 256 + threadIdx.x;
    if (e >= N_EDGES) return;
    int seg = edst[e] * NUM_REL + erel[e];
    int pos = offs[seg] + atomicAdd(&cursor[seg], 1);
    csre[pos] = e;
}

// ================= aggregation (gather) =================
// layer 1: segX[seg,:256] = sum x[src], segEF[seg,:64] = sum ef[e], cnt[seg]
__global__ __launch_bounds__(256) void agg1(
    const float* __restrict__ x, const float* __restrict__ ef,
    const int* __restrict__ esrc, const int* __restrict__ offs, const int* __restrict__ hist,
    const int* __restrict__ csre,
    float* __restrict__ segX, float* __restrict__ segEF, float* __restrict__ cnt)
{
    int seg = blockIdx.x * 4 + (threadIdx.x >> 6);
    int lane = threadIdx.x & 63;
    int beg = offs[seg], end = beg + hist[seg];
    float4 acc = make_float4(0.f, 0.f, 0.f, 0.f);
    float accef = 0.f;
    for (int i = beg; i < end; ++i) {
        int e = csre[i];
        int src = esrc[e];
        float4 v = *(const float4*)(x + (size_t)src * NODE_DIM + lane * 4);
        acc.x += v.x; acc.y += v.y; acc.z += v.z; acc.w += v.w;
        accef += ef[(size_t)e * EDGE_DIM + lane];
    }
    *(float4*)(segX + (size_t)seg * NODE_DIM + lane * 4) = acc;
    segEF[(size_t)seg * EDGE_DIM + lane] = accef;
    if (lane == 0) cnt[seg] = (float)(end - beg);
}

// layer 2: S2[seg,:128] = sum P[src, r*128:(r+1)*128], r = seg & 3
__global__ __launch_bounds__(256) void agg2(
    const float* __restrict__ P,
    const int* __restrict__ esrc, const int* __restrict__ offs, const int* __restrict__ hist,
    const int* __restrict__ csre, float* __restrict__ S2)
{
    int seg = blockIdx.x * 4 + (threadIdx.x >> 6);
    int lane = threadIdx.x & 63;
    int r = seg & 3;
    int beg = offs[seg], end = beg + hist[seg];
    float2 acc = make_float2(0.f, 0.f);
    for (int i = beg; i < end; ++i) {
        int e = csre[i];
        int src = esrc[e];
        float2 v = *(const float2*)(P + (size_t)src * HID + r * LAST + lane * 2);
        acc.x += v.x; acc.y += v.y;
    }
    *(float2*)(S2 + (size_t)seg * LAST + lane * 2) = acc;
}

// ================= finalize layer-1 seg means =================
__global__ __launch_bounds__(256) void finalize_seg(
    float* __restrict__ segX, const float* __restrict__ cnt, const float* __restrict__ be,
    int dlog2)
{
    size_t i = (size_t)blockIdx.x * 256 + threadIdx.x;
    size_t base = i * 4;
    int D = 1 << dlog2;
    int s = (int)(base >> dlog2);
    int c = (int)(base & (D - 1));
    float ct = cnt[s];
    float inv = 1.0f / (ct + EPS);
    float4 v = ((float4*)segX)[i];
    float4 b = *(const float4*)(be + c);
    v.x = (v.x + ct * b.x) * inv;
    v.y = (v.y + ct * b.y) * inv;
    v.z = (v.z + ct * b.z) * inv;
    v.w = (v.w + ct * b.w) * inv;
    ((float4*)segX)[i] = v;
}

// ================= generic fp32 GEMM: C = act(A @ W^T + bias [+ C_in]) ============
// A [M,K] rows stride lda, W [N,K] packed, C rows stride ldc; N%64==0, K%16==0
#define BM 64
#define BN 64
#define BK 16

template<int RELU, int ACC>
__global__ __launch_bounds__(256) void gemm_nt(
    const float* __restrict__ A, const float* __restrict__ W,
    float* __restrict__ C, const float* __restrict__ bias,
    int M, int N, int K, int lda, int ldc)
{
    __shared__ float As[BK][BM + 4];
    __shared__ float Ws[BK][BN + 4];
    int row0 = blockIdx.x * BM;
    int col0 = blockIdx.y * BN;
    int tid = threadIdx.x;
    int lr = tid >> 2;
    int lc = (tid & 3) * 4;
    int ty = tid >> 4, tx = tid & 15;
    float acc[4][4] = {};

    for (int k0 = 0; k0 < K; k0 += BK) {
        int gr = row0 + lr;
        float4 v = make_float4(0.f, 0.f, 0.f, 0.f);
        if (gr < M) v = *(const float4*)(A + (size_t)gr * lda + k0 + lc);
        As[lc + 0][lr] = v.x; As[lc + 1][lr] = v.y; As[lc + 2][lr] = v.z; As[lc + 3][lr] = v.w;
        int gc = col0 + lr;
        float4 w = *(const float4*)(W + (size_t)gc * K + k0 + lc);
        Ws[lc + 0][lr] = w.x; Ws[lc + 1][lr] = w.y; Ws[lc + 2][lr] = w.z; Ws[lc + 3][lr] = w.w;
        __syncthreads();
#pragma unroll
        for (int kk = 0; kk < BK; ++kk) {
            float4 av = *(const float4*)&As[kk][ty * 4];
            float4 bv = *(const float4*)&Ws[kk][tx * 4];
            float a[4] = {av.x, av.y, av.z, av.w};
            float b[4] = {bv.x, bv.y, bv.z, bv.w};
#pragma unroll
            for (int i = 0; i < 4; ++i)
#pragma unroll
                for (int j = 0; j < 4; ++j)
                    acc[i][j] += a[i] * b[j];
        }
        __syncthreads();
    }

    int gr0 = row0 + ty * 4;
    int gc0 = col0 + tx * 4;
#pragma unroll
    for (int i = 0; i < 4; ++i) {
        int gr = gr0 + i;
        if (gr >= M) continue;
        float* cp = C + (size_t)gr * ldc + gc0;
#pragma unroll
        for (int j = 0; j < 4; ++j) {
            float v = acc[i][j];
            if (bias) v += bias[gc0 + j];
            if (ACC) v += cp[j];
            if (RELU) v = fmaxf(v, 0.f);
            cp[j] = v;
        }
    }
}

// ================= layer-2 weight prep =================
// W2p[r*128+j][k] = Wl2[j][r*512+k]
__global__ __launch_bounds__(256) void permuteW2(
    const float* __restrict__ Wl2, float* __restrict__ W2p)
{
    int idx = blockIdx.x * 256 + threadIdx.x;   // 0 .. 512*512-1
    int row = idx >> 9;
    int k = idx & 511;
    int r = row >> 7, j = row & 127;
    W2p[idx] = Wl2[j * (NUM_REL * HID) + r * HID + k];
}

// Wc[row][c] = sum_k W2p[row][k] * We2[k][c]   (row<512, c<64)
__global__ __launch_bounds__(64) void wc_kernel(
    const float* __restrict__ W2p, const float* __restrict__ We2, float* __restrict__ Wc)
{
    int row = blockIdx.x;
    int c = threadIdx.x;
    float acc = 0.f;
    for (int k = 0; k < HID; ++k)
        acc += W2p[row * HID + k] * We2[k * EDGE_DIM + c];
    Wc[row * EDGE_DIM + c] = acc;
}

// bvec[row] = sum_k W2p[row][k] * be2[k]
__global__ __launch_bounds__(256) void bvec_kernel(
    const float* __restrict__ W2p, const float* __restrict__ be2, float* __restrict__ bvec)
{
    int row = blockIdx.x * 256 + threadIdx.x;
    if (row >= 512) return;
    float acc = 0.f;
    for (int k = 0; k < HID; ++k) acc += W2p[row * HID + k] * be2[k];
    bvec[row] = acc;
}

// h2[n,j] = relu(h2[n,j] + bl2[j] + sum_r (S2[n*4+r,j] + cnt*bvec[r*128+j])/(cnt+eps))
__global__ __launch_bounds__(256) void combine2(
    float* __restrict__ h2, const float* __restrict__ S2, const float* __restrict__ cnt,
    const float* __restrict__ bvec, const float* __restrict__ bl2)
{
    int n = blockIdx.x * 2 + (threadIdx.x >> 7);
    int j = threadIdx.x & 127;
    float v = h2[(size_t)n * LAST + j] + bl2[j];
#pragma unroll
    for (int r = 0; r < 4; ++r) {
        float c = cnt[n * 4 + r];
        v += (S2[(size_t)(n * 4 + r) * LAST + j] + c * bvec[r * LAST + j]) / (c + EPS);
    }
    h2[(size_t)n * LAST + j] = fmaxf(v, 0.f);
}

// ================= head =================
__global__ __launch_bounds__(256) void gather_head(
    const int* __restrict__ inputs, const float* __restrict__ h2,
    const float* __restrict__ ef, float* __restrict__ xcat, float* __restrict__ ef_g)
{
    int i = blockIdx.x;
    int t = threadIdx.x;
    int d1 = inputs[i * 3 + 0];
    int d2 = inputs[i * 3 + 1];
    int ctx = inputs[i * 3 + 2];
    if (t < 128) {
        xcat[(size_t)i * 384 + t] = h2[(size_t)d1 * LAST + t];
    } else {
        int c = t - 128;
        xcat[(size_t)i * 384 + 128 + c] = h2[(size_t)d2 * LAST + c];
    }
    if (t < 64) ef_g[(size_t)i * 64 + t] = ef[(size_t)ctx * EDGE_DIM + t];
}

__global__ __launch_bounds__(256) void final_matvec(
    const float* __restrict__ f2, const float* __restrict__ Wf3,
    const float* __restrict__ bf3, float* __restrict__ out, int M)
{
    int row = blockIdx.x * 4 + (threadIdx.x >> 6);
    int lane = threadIdx.x & 63;
    if (row >= M) return;
    float v = f2[(size_t)row * 64 + lane] * Wf3[lane];
#pragma unroll
    for (int off = 32; off > 0; off >>= 1) v += __shfl_down(v, off);
    if (lane == 0) out[row] = v + bf3[0];
}

extern "C" void kernel_launch(void* const* d_in, const int* in_sizes, int n_in,
                              void* d_out, int out_size, void* d_ws, size_t ws_size,
                              hipStream_t stream)
{
    const int*   inputs       = (const int*)  d_in[0];
    const float* node_feature = (const float*)d_in[1];
    const float* edge_feature = (const float*)d_in[2];
    const int*   edge_src     = (const int*)  d_in[3];
    const int*   edge_dst     = (const int*)  d_in[4];
    const int*   edge_rel     = (const int*)  d_in[5];
    const float* We1 = (const float*)d_in[6];
    const float* be1 = (const float*)d_in[7];
    const float* Wl1 = (const float*)d_in[8];
    const float* bl1 = (const float*)d_in[9];
    const float* Ws1 = (const float*)d_in[10];
    const float* bs1 = (const float*)d_in[11];
    const float* We2 = (const float*)d_in[12];
    const float* be2 = (const float*)d_in[13];
    const float* Wl2 = (const float*)d_in[14];
    const float* bl2 = (const float*)d_in[15];
    const float* Ws2 = (const float*)d_in[16];
    const float* bs2 = (const float*)d_in[17];
    const float* Wc1 = (const float*)d_in[18];
    const float* bc1 = (const float*)d_in[19];
    const float* Wc2 = (const float*)d_in[20];
    const float* bc2 = (const float*)d_in[21];
    const float* Wf1 = (const float*)d_in[22];
    const float* bf1 = (const float*)d_in[23];
    const float* Wf2 = (const float*)d_in[24];
    const float* bf2 = (const float*)d_in[25];
    const float* Wf3 = (const float*)d_in[26];
    const float* bf3 = (const float*)d_in[27];
    float* out = (float*)d_out;

    // ---- workspace layout ----
    float* cnt    = (float*)d_ws;              // 200000 f
    int*   hist   = (int*)(cnt + NSEG);        // 200000 i
    int*   offs   = hist + NSEG;               // 200000 i
    int*   cursor = offs + NSEG;               // 200000 i
    int*   csre   = cursor + NSEG;             // 800000 i
    int*   bsums  = csre + N_EDGES;            // 128 i
    float* W2p    = (float*)(bsums + 128);     // 262144 f
    float* Wc     = W2p + 512 * 512;           // 32768 f
    float* bvec   = Wc + 512 * 64;             // 512 f
    float* segX1  = bvec + 512;                                  // 51,200,000 f
    float* segEF  = segX1 + (size_t)NSEG * NODE_DIM;             // 12,800,000 f
    float* h1     = segEF + (size_t)NSEG * EDGE_DIM;             // 25,600,000 f
    float* P      = h1 + (size_t)N_NODES * HID;                  // 25,600,000 f
    float* S2     = P + (size_t)N_NODES * HID;                   // 25,600,000 f
    float* h2     = S2 + (size_t)NSEG * LAST;                    //  6,400,000 f
    // head buffers alias segX1 (dead after the Wl1 GEMM)
    float* ef_g = segX1;
    float* u3   = ef_g + (size_t)BATCH * 64;
    float* xcat = u3 + (size_t)BATCH * 256;
    float* f1   = xcat + (size_t)BATCH * 384;
    float* f2   = f1 + (size_t)BATCH * 128;

    // ---- CSR build ----
    hipMemsetAsync(hist, 0, NSEG * sizeof(int), stream);
    hipMemsetAsync(cursor, 0, NSEG * sizeof(int), stream);
    hist_kernel<<<(N_EDGES + 255) / 256, 256, 0, stream>>>(edge_dst, edge_rel, hist);
    int nscan = (NSEG + SCAN_B - 1) / SCAN_B;   // 98
    scan1<<<nscan, 256, 0, stream>>>(hist, offs, bsums, NSEG);
    scan2<<<1, 64, 0, stream>>>(bsums, nscan);
    scan3<<<nscan, 256, 0, stream>>>(offs, bsums, NSEG);
    csr_fill<<<(N_EDGES + 255) / 256, 256, 0, stream>>>(edge_dst, edge_rel, offs, cursor, csre);

    // ---- layer 2 weight prep (no deps on layer 1) ----
    permuteW2<<<(512 * 512) / 256, 256, 0, stream>>>(Wl2, W2p);
    wc_kernel<<<512, 64, 0, stream>>>(W2p, We2, Wc);
    bvec_kernel<<<2, 256, 0, stream>>>(W2p, be2, bvec);

    // ---- layer 1 ----
    agg1<<<NSEG / 4, 256, 0, stream>>>(node_feature, edge_feature, edge_src,
                                       offs, hist, csre, segX1, segEF, cnt);
    {   // segX1 += segEF @ We1^T
        dim3 g((NSEG + BM - 1) / BM, NODE_DIM / BN);
        gemm_nt<0, 1><<<g, 256, 0, stream>>>(segEF, We1, segX1, nullptr,
                                             NSEG, NODE_DIM, EDGE_DIM, EDGE_DIM, NODE_DIM);
    }
    finalize_seg<<<(unsigned)((size_t)NSEG * NODE_DIM / 4 / 256), 256, 0, stream>>>(segX1, cnt, be1, 8);
    {
        dim3 g((N_NODES + BM - 1) / BM, HID / BN);
        gemm_nt<0, 0><<<g, 256, 0, stream>>>(segX1, Wl1, h1, bl1,
                                             N_NODES, HID, NUM_REL * NODE_DIM, NUM_REL * NODE_DIM, HID);
        gemm_nt<1, 1><<<g, 256, 0, stream>>>(node_feature, Ws1, h1, bs1,
                                             N_NODES, HID, NODE_DIM, NODE_DIM, HID);
    }

    // ---- layer 2 ----
    {   // P = h1 @ W2p^T   [50000,512] x [512,512]^T
        dim3 g((N_NODES + BM - 1) / BM, HID / BN);
        gemm_nt<0, 0><<<g, 256, 0, stream>>>(h1, W2p, P, nullptr,
                                             N_NODES, HID, HID, HID, HID);
    }
    agg2<<<NSEG / 4, 256, 0, stream>>>(P, edge_src, offs, hist, csre, S2);
    for (int r = 0; r < NUM_REL; ++r) {   // S2[.,r] += segEF[.,r] @ Wc_r^T (strided)
        dim3 g((N_NODES + BM - 1) / BM, LAST / BN);
        gemm_nt<0, 1><<<g, 256, 0, stream>>>(segEF + r * EDGE_DIM, Wc + r * LAST * EDGE_DIM,
                                             S2 + r * LAST, nullptr,
                                             N_NODES, LAST, EDGE_DIM,
                                             NUM_REL * EDGE_DIM, NUM_REL * LAST);
    }
    {   // h2 = h1 @ Ws2^T + bs2
        dim3 g((N_NODES + BM - 1) / BM, LAST / BN);
        gemm_nt<0, 0><<<g, 256, 0, stream>>>(h1, Ws2, h2, bs2,
                                             N_NODES, LAST, HID, HID, LAST);
    }
    combine2<<<N_NODES / 2, 256, 0, stream>>>(h2, S2, cnt, bvec, bl2);

    // ---- head ----
    gather_head<<<BATCH, 256, 0, stream>>>(inputs, h2, edge_feature, xcat, ef_g);
    {
        dim3 g(BATCH / BM, 256 / BN);
        gemm_nt<1, 0><<<g, 256, 0, stream>>>(ef_g, Wc1, u3, bc1, BATCH, 256, 64, 64, 256);
    }
    {
        dim3 g(BATCH / BM, LAST / BN);
        gemm_nt<0, 0><<<g, 256, 0, stream>>>(u3, Wc2, xcat + 256, bc2, BATCH, LAST, 256, 256, 384);
    }
    {
        dim3 g(BATCH / BM, LAST / BN);
        gemm_nt<1, 0><<<g, 256, 0, stream>>>(xcat, Wf1, f1, bf1, BATCH, LAST, 384, 384, LAST);
    }
    {
        dim3 g(BATCH / BM, 64 / BN);
        gemm_nt<1, 0><<<g, 256, 0, stream>>>(f1, Wf2, f2, bf2, BATCH, 64, LAST, LAST, 64);
    }
    final_matvec<<<BATCH / 4, 256, 0, stream>>>(f2, Wf3, bf3, out, BATCH);
}

// Round 3
// 988.016 us; speedup vs baseline: 16.4340x; 2.4263x over previous
//
#include <hip/hip_runtime.h>
#include <hip/hip_bf16.h>

#define N_NODES 50000
#define N_EDGES 800000
#define NODE_DIM 256
#define EDGE_DIM 64
#define NUM_REL 4
#define HID 512
#define LAST 128
#define BATCH 16384
#define EPS 1e-10f
#define NSEG (N_NODES * NUM_REL)

#define K1 1568   // meanX 1024 | E1 256 | x 256 | f 4 | pad 28
#define K2 800    // E1 256 | h1 512 | f 4 | pad 28

typedef __bf16 bf16_t;
typedef __attribute__((ext_vector_type(8))) __bf16 bf16x8;
typedef __attribute__((ext_vector_type(4))) __bf16 bf16x4;
typedef __attribute__((ext_vector_type(2))) __bf16 bf16x2;
typedef __attribute__((ext_vector_type(4))) float f32x4;

// ================= CSR build =================
__global__ __launch_bounds__(256) void hist_kernel(
    const int* __restrict__ edst, const int* __restrict__ erel, int* __restrict__ hist)
{
    int e = blockIdx.x * 256 + threadIdx.x;
    if (e >= N_EDGES) return;
    atomicAdd(&hist[edst[e] * NUM_REL + erel[e]], 1);
}

#define SCAN_B 2048
__global__ __launch_bounds__(256) void scan1(
    const int* __restrict__ in, int* __restrict__ out, int* __restrict__ bsum, int n)
{
    __shared__ int sh[256];
    int base = blockIdx.x * SCAN_B + threadIdx.x * 8;
    int v[8]; int s = 0;
#pragma unroll
    for (int i = 0; i < 8; ++i) {
        int idx = base + i;
        v[i] = s;
        s += (idx < n) ? in[idx] : 0;
    }
    sh[threadIdx.x] = s;
    __syncthreads();
    for (int off = 1; off < 256; off <<= 1) {
        int t = (threadIdx.x >= off) ? sh[threadIdx.x - off] : 0;
        __syncthreads();
        sh[threadIdx.x] += t;
        __syncthreads();
    }
    int texcl = (threadIdx.x == 0) ? 0 : sh[threadIdx.x - 1];
#pragma unroll
    for (int i = 0; i < 8; ++i) {
        int idx = base + i;
        if (idx < n) out[idx] = texcl + v[i];
    }
    if (threadIdx.x == 255) bsum[blockIdx.x] = sh[255];
}

__global__ void scan2(int* bsum, int nb)
{
    if (threadIdx.x == 0 && blockIdx.x == 0) {
        int s = 0;
        for (int i = 0; i < nb; ++i) { int t = bsum[i]; bsum[i] = s; s += t; }
    }
}

__global__ __launch_bounds__(256) void scan3(int* __restrict__ out, const int* __restrict__ bsum, int n)
{
    int idx = blockIdx.x * SCAN_B + threadIdx.x * 8;
    int add = bsum[blockIdx.x];
#pragma unroll
    for (int i = 0; i < 8; ++i)
        if (idx + i < n) out[idx + i] += add;
}

__global__ __launch_bounds__(256) void csr_fill(
    const int* __restrict__ edst, const int* __restrict__ erel,
    const int* __restrict__ offs, int* __restrict__ cursor, int* __restrict__ csre)
{
    int e = blockIdx.x * 256 + threadIdx.x;
    if (e >= N_EDGES) return;
    int seg = edst[e] * NUM_REL + erel[e];
    int pos = offs[seg] + atomicAdd(&cursor[seg], 1);
    csre[pos] = e;
}

// ================= converts =================
__global__ __launch_bounds__(256) void f2bf4_k(const float* __restrict__ src, bf16_t* __restrict__ dst, int n4)
{
    int i = blockIdx.x * 256 + threadIdx.x;
    if (i >= n4) return;
    float4 v = ((const float4*)src)[i];
    bf16x4 o;
    o[0] = (bf16_t)v.x; o[1] = (bf16_t)v.y; o[2] = (bf16_t)v.z; o[3] = (bf16_t)v.w;
    ((bf16x4*)dst)[i] = o;
}

__global__ __launch_bounds__(256) void addbias_k(const float* __restrict__ a, const float* __restrict__ b,
                                                 float* __restrict__ o, int n)
{
    int i = blockIdx.x * 256 + threadIdx.x;
    if (i < n) o[i] = a[i] + b[i];
}

// x (fp32 [50000,256]) -> A1 cols 1280..1535 (bf16)
__global__ __launch_bounds__(256) void xconv_k(const float* __restrict__ x, bf16_t* __restrict__ A1)
{
    int i = blockIdx.x * 256 + threadIdx.x;   // over 50000*64
    int n = i >> 6;
    int c4 = i & 63;
    float4 v = ((const float4*)(x + (size_t)n * 256))[c4];
    bf16x4 o;
    o[0] = (bf16_t)v.x; o[1] = (bf16_t)v.y; o[2] = (bf16_t)v.z; o[3] = (bf16_t)v.w;
    *(bf16x4*)(A1 + (size_t)n * K1 + 1280 + c4 * 4) = o;
}

// ================= weight prep =================
// W1cat[j, 0:1024]=Wl1[j]; [1024+r*64+e]=sum_c Wl1[j,r*256+c]*We1[c,e];
// [1280:1536]=Ws1[j]; [1536+r]=Wl1_r[j]·be1; [1540:1568]=0
__global__ __launch_bounds__(256) void prep_w1cat(
    const float* __restrict__ Wl1, const float* __restrict__ We1,
    const float* __restrict__ Ws1, const float* __restrict__ be1, bf16_t* __restrict__ W1cat)
{
    int j = blockIdx.x;
    int t = threadIdx.x;
    const float* wrow = Wl1 + (size_t)j * 1024;
    bf16_t* out = W1cat + (size_t)j * K1;
    for (int c = t; c < 1024; c += 256) out[c] = (bf16_t)wrow[c];
    {
        int r = t >> 6, e = t & 63;
        float s = 0.f;
        const float* wr = wrow + r * 256;
        for (int c = 0; c < 256; ++c) s += wr[c] * We1[c * 64 + e];
        out[1024 + t] = (bf16_t)s;
    }
    if (t < 256) out[1280 + t] = (bf16_t)Ws1[(size_t)j * 256 + t];
    if (t < 4) {
        float s = 0.f;
        const float* wr = wrow + t * 256;
        for (int c = 0; c < 256; ++c) s += wr[c] * be1[c];
        out[1536 + t] = (bf16_t)s;
    }
    if (t >= 4 && t < 32) out[1536 + t] = (bf16_t)0.f;
}

// W2cat[j, r*64+e]=sum_k Wl2[j,r*512+k]*We2[k,e]; [256:768]=Ws2[j]; [768+r]=Wl2_r[j]·be2; [772:800]=0
__global__ __launch_bounds__(256) void prep_w2cat(
    const float* __restrict__ Wl2, const float* __restrict__ We2,
    const float* __restrict__ Ws2, const float* __restrict__ be2, bf16_t* __restrict__ W2cat)
{
    int j = blockIdx.x;
    int t = threadIdx.x;
    const float* wrow = Wl2 + (size_t)j * 2048;
    bf16_t* out = W2cat + (size_t)j * K2;
    {
        int r = t >> 6, e = t & 63;
        float s = 0.f;
        const float* wr = wrow + r * 512;
        for (int k = 0; k < 512; ++k) s += wr[k] * We2[k * 64 + e];
        out[t] = (bf16_t)s;
    }
    for (int c = t; c < 512; c += 256) out[256 + c] = (bf16_t)Ws2[(size_t)j * 512 + c];
    if (t < 4) {
        float s = 0.f;
        const float* wr = wrow + t * 512;
        for (int k = 0; k < 512; ++k) s += wr[k] * be2[k];
        out[768 + t] = (bf16_t)s;
    }
    if (t >= 4 && t < 32) out[768 + t] = (bf16_t)0.f;
}

// W2p[r*128+j, k] = Wl2[j, r*512+k]
__global__ __launch_bounds__(256) void prep_w2p(const float* __restrict__ Wl2, bf16_t* __restrict__ W2p)
{
    int idx = blockIdx.x * 256 + threadIdx.x;    // 512*512
    int row = idx >> 9, k = idx & 511;
    int j = row & 127, r = row >> 7;
    W2p[idx] = (bf16_t)Wl2[(size_t)j * 2048 + r * 512 + k];
}

// ================= aggregation =================
// block = node n; wave w = relation r. Writes bf16 means into A1 and A2.
__global__ __launch_bounds__(256) void agg1(
    const bf16_t* __restrict__ efb,
    const int* __restrict__ esrc, const int* __restrict__ offs, const int* __restrict__ hist,
    const int* __restrict__ csre,
    bf16_t* __restrict__ A1, bf16_t* __restrict__ A2)
{
    int n = blockIdx.x;
    int w = threadIdx.x >> 6;
    int lane = threadIdx.x & 63;
    int seg = n * NUM_REL + w;
    int beg = offs[seg], ct = hist[seg];
    float a0 = 0.f, a1 = 0.f, a2 = 0.f, a3 = 0.f, aef = 0.f;
    for (int i = 0; i < ct; ++i) {
        int e = csre[beg + i];
        int src = esrc[e];
        bf16x4 v = *(const bf16x4*)(A1 + (size_t)src * K1 + 1280 + lane * 4);
        a0 += (float)v[0]; a1 += (float)v[1]; a2 += (float)v[2]; a3 += (float)v[3];
        aef += (float)efb[(size_t)e * 64 + lane];
    }
    float inv = 1.0f / ((float)ct + EPS);
    bf16x4 m;
    m[0] = (bf16_t)(a0 * inv); m[1] = (bf16_t)(a1 * inv);
    m[2] = (bf16_t)(a2 * inv); m[3] = (bf16_t)(a3 * inv);
    *(bf16x4*)(A1 + (size_t)n * K1 + w * 256 + lane * 4) = m;
    bf16_t ev = (bf16_t)(aef * inv);
    A1[(size_t)n * K1 + 1024 + w * 64 + lane] = ev;
    A2[(size_t)n * K2 + w * 64 + lane] = ev;
    if (lane == 0) {
        bf16_t fv = (bf16_t)((float)ct * inv);
        A1[(size_t)n * K1 + 1536 + w] = fv;
        A2[(size_t)n * K2 + 768 + w] = fv;
    }
    if (w == 3) {
        if (lane >= 4 && lane < 32)  A1[(size_t)n * K1 + 1536 + lane] = (bf16_t)0.f;
        if (lane >= 36 && lane < 64) A2[(size_t)n * K2 + 772 + (lane - 36)] = (bf16_t)0.f;
    }
}

// block = node n; wave w = relation r; sum P[src, r*128:...] -> mean; cross-wave reduce -> h2base fp32
__global__ __launch_bounds__(256) void agg2(
    const bf16_t* __restrict__ P,
    const int* __restrict__ esrc, const int* __restrict__ offs, const int* __restrict__ hist,
    const int* __restrict__ csre, float* __restrict__ h2base)
{
    __shared__ float red[4][128];
    int n = blockIdx.x;
    int w = threadIdx.x >> 6;
    int lane = threadIdx.x & 63;
    int seg = n * NUM_REL + w;
    int beg = offs[seg], ct = hist[seg];
    float s0 = 0.f, s1 = 0.f;
    for (int i = 0; i < ct; ++i) {
        int e = csre[beg + i];
        int src = esrc[e];
        bf16x2 v = *(const bf16x2*)(P + (size_t)src * HID + w * 128 + lane * 2);
        s0 += (float)v[0]; s1 += (float)v[1];
    }
    float inv = 1.0f / ((float)ct + EPS);
    red[w][lane * 2] = s0 * inv;
    red[w][lane * 2 + 1] = s1 * inv;
    __syncthreads();
    int t = threadIdx.x;
    if (t < 128)
        h2base[(size_t)n * 128 + t] = red[0][t] + red[1][t] + red[2][t] + red[3][t];
}

// ================= bf16 MFMA GEMM =================
// C = act(A[M,K]@W[N,K]^T + bias [+ Cin]); 128x128 tile, BK=32, 4 waves, XOR-swizzled LDS
template<int RELU, int ACC, int OUTBF>
__global__ __launch_bounds__(256) void gemm_bf16(
    const bf16_t* __restrict__ A, int lda,
    const bf16_t* __restrict__ W, int ldw,
    const float* __restrict__ Cin, int ldcin,
    const float* __restrict__ bias,
    void* __restrict__ Cout, int ldc,
    int M, int N, int K)
{
    __shared__ char smem[16384];
    char* As = smem;
    char* Bs = smem + 8192;
    const int tid = threadIdx.x;
    const int row0 = blockIdx.x * 128;
    const int col0 = blockIdx.y * 128;

    // staging: thread t handles row t>>1, chunks {0,1} or {2,3} (8 bf16 each)
    const int srow = tid >> 1;
    const int skc = (tid & 1) * 2;
    const int sswz = (srow >> 1) & 3;
    const int ld0 = srow * 64 + ((skc) ^ sswz) * 16;
    const int ld1 = srow * 64 + ((skc + 1) ^ sswz) * 16;
    int garow = row0 + srow; if (garow >= M) garow = M - 1;
    int gbrow = col0 + srow; if (gbrow >= N) gbrow = N - 1;
    const bf16_t* Aptr = A + (size_t)garow * lda + skc * 8;
    const bf16_t* Wptr = W + (size_t)gbrow * ldw + skc * 8;

    // compute-phase addressing
    const int lane = tid & 63, wv = tid >> 6;
    const int wm = wv >> 1, wn = wv & 1;
    const int r16 = lane & 15, kch = lane >> 4;
    const int arow = wm * 64 + r16;
    const int aoff = arow * 64 + ((kch ^ ((arow >> 1) & 3)) << 4);
    const int brow = wn * 64 + r16;
    const int boff = brow * 64 + ((kch ^ ((brow >> 1) & 3)) << 4);

    f32x4 zero = {0.f, 0.f, 0.f, 0.f};
    f32x4 acc[4][4];
#pragma unroll
    for (int i = 0; i < 4; ++i)
#pragma unroll
        for (int j = 0; j < 4; ++j) acc[i][j] = zero;

    uint4 pa0 = *(const uint4*)(Aptr);
    uint4 pa1 = *(const uint4*)(Aptr + 8);
    uint4 pb0 = *(const uint4*)(Wptr);
    uint4 pb1 = *(const uint4*)(Wptr + 8);

    for (int k0 = 0; k0 < K; k0 += 32) {
        *(uint4*)(As + ld0) = pa0;
        *(uint4*)(As + ld1) = pa1;
        *(uint4*)(Bs + ld0) = pb0;
        *(uint4*)(Bs + ld1) = pb1;
        __syncthreads();
        if (k0 + 32 < K) {
            const bf16_t* ap = Aptr + (k0 + 32);
            const bf16_t* wp = Wptr + (k0 + 32);
            pa0 = *(const uint4*)ap;
            pa1 = *(const uint4*)(ap + 8);
            pb0 = *(const uint4*)wp;
            pb1 = *(const uint4*)(wp + 8);
        }
        bf16x8 af[4], bfr[4];
#pragma unroll
        for (int i = 0; i < 4; ++i) af[i] = *(const bf16x8*)(As + aoff + i * 1024);
#pragma unroll
        for (int j = 0; j < 4; ++j) bfr[j] = *(const bf16x8*)(Bs + boff + j * 1024);
#pragma unroll
        for (int i = 0; i < 4; ++i)
#pragma unroll
            for (int j = 0; j < 4; ++j)
                acc[i][j] = __builtin_amdgcn_mfma_f32_16x16x32_bf16(af[i], bfr[j], acc[i][j], 0, 0, 0);
        __syncthreads();
    }

    const int crow0 = row0 + wm * 64;
#pragma unroll
    for (int i = 0; i < 4; ++i) {
#pragma unroll
        for (int j = 0; j < 4; ++j) {
            int col = col0 + wn * 64 + j * 16 + r16;
            if (col >= N) continue;
            float bv = bias ? bias[col] : 0.f;
#pragma unroll
            for (int q = 0; q < 4; ++q) {
                int row = crow0 + i * 16 + kch * 4 + q;
                if (row >= M) continue;
                float v = acc[i][j][q] + bv;
                if (ACC) v += Cin[(size_t)row * ldcin + col];
                if (RELU) v = fmaxf(v, 0.f);
                if (OUTBF) ((bf16_t*)Cout)[(size_t)row * ldc + col] = (bf16_t)v;
                else       ((float*)Cout)[(size_t)row * ldc + col] = v;
            }
        }
    }
}

// ================= head =================
__global__ __launch_bounds__(256) void gather_head(
    const int* __restrict__ inputs, const bf16_t* __restrict__ h2,
    const bf16_t* __restrict__ efb, bf16_t* __restrict__ xcat, bf16_t* __restrict__ ef_g)
{
    int i = blockIdx.x;
    int t = threadIdx.x;
    int d1 = inputs[i * 3 + 0];
    int d2 = inputs[i * 3 + 1];
    int ctx = inputs[i * 3 + 2];
    if (t < 128) {
        xcat[(size_t)i * 384 + t] = h2[(size_t)d1 * LAST + t];
    } else {
        int c = t - 128;
        xcat[(size_t)i * 384 + 128 + c] = h2[(size_t)d2 * LAST + c];
    }
    if (t < 64) ef_g[(size_t)i * 64 + t] = efb[(size_t)ctx * 64 + t];
}

__global__ __launch_bounds__(256) void final_matvec(
    const bf16_t* __restrict__ f2, const float* __restrict__ Wf3,
    const float* __restrict__ bf3, float* __restrict__ out, int M)
{
    int row = blockIdx.x * 4 + (threadIdx.x >> 6);
    int lane = threadIdx.x & 63;
    if (row >= M) return;
    float v = (float)f2[(size_t)row * 64 + lane] * Wf3[lane];
#pragma unroll
    for (int off = 32; off > 0; off >>= 1) v += __shfl_down(v, off);
    if (lane == 0) out[row] = v + bf3[0];
}

extern "C" void kernel_launch(void* const* d_in, const int* in_sizes, int n_in,
                              void* d_out, int out_size, void* d_ws, size_t ws_size,
                              hipStream_t stream)
{
    const int*   inputs       = (const int*)  d_in[0];
    const float* node_feature = (const float*)d_in[1];
    const float* edge_feature = (const float*)d_in[2];
    const int*   edge_src     = (const int*)  d_in[3];
    const int*   edge_dst     = (const int*)  d_in[4];
    const int*   edge_rel     = (const int*)  d_in[5];
    const float* We1 = (const float*)d_in[6];
    const float* be1 = (const float*)d_in[7];
    const float* Wl1 = (const float*)d_in[8];
    const float* bl1 = (const float*)d_in[9];
    const float* Ws1 = (const float*)d_in[10];
    const float* bs1 = (const float*)d_in[11];
    const float* We2 = (const float*)d_in[12];
    const float* be2 = (const float*)d_in[13];
    const float* Wl2 = (const float*)d_in[14];
    const float* bl2 = (const float*)d_in[15];
    const float* Ws2 = (const float*)d_in[16];
    const float* bs2 = (const float*)d_in[17];
    const float* Wc1 = (const float*)d_in[18];
    const float* bc1 = (const float*)d_in[19];
    const float* Wc2 = (const float*)d_in[20];
    const float* bc2 = (const float*)d_in[21];
    const float* Wf1 = (const float*)d_in[22];
    const float* bf1 = (const float*)d_in[23];
    const float* Wf2 = (const float*)d_in[24];
    const float* bf2 = (const float*)d_in[25];
    const float* Wf3 = (const float*)d_in[26];
    const float* bf3 = (const float*)d_in[27];
    float* out = (float*)d_out;

    // ---- workspace layout (256B aligned chunks) ----
    char* p = (char*)d_ws;
    auto alloc = [&](size_t bytes) { char* r = p; p += (bytes + 255) & ~(size_t)255; return r; };
    int* hist    = (int*)alloc(NSEG * 4);
    int* offs    = (int*)alloc(NSEG * 4);
    int* cursor  = (int*)alloc(NSEG * 4);
    int* csre    = (int*)alloc(N_EDGES * 4);
    int* bsums   = (int*)alloc(128 * 4);
    bf16_t* A1    = (bf16_t*)alloc((size_t)N_NODES * K1 * 2);
    bf16_t* A2    = (bf16_t*)alloc((size_t)N_NODES * K2 * 2);
    bf16_t* Pbuf  = (bf16_t*)alloc((size_t)N_NODES * HID * 2);
    bf16_t* efb   = (bf16_t*)alloc((size_t)N_EDGES * 64 * 2);
    float*  h2base= (float*)alloc((size_t)N_NODES * 128 * 4);
    bf16_t* h2    = (bf16_t*)alloc((size_t)N_NODES * 128 * 2);
    bf16_t* W1cat = (bf16_t*)alloc((size_t)512 * K1 * 2);
    bf16_t* W2cat = (bf16_t*)alloc((size_t)128 * K2 * 2);
    bf16_t* W2p   = (bf16_t*)alloc((size_t)512 * 512 * 2);
    bf16_t* Wc1b  = (bf16_t*)alloc(256 * 64 * 2);
    bf16_t* Wc2b  = (bf16_t*)alloc(128 * 256 * 2);
    bf16_t* Wf1b  = (bf16_t*)alloc(128 * 384 * 2);
    bf16_t* Wf2b  = (bf16_t*)alloc(64 * 128 * 2);
    float*  bias12= (float*)alloc(512 * 4);
    float*  bias22= (float*)alloc(128 * 4);
    bf16_t* ef_g  = (bf16_t*)alloc((size_t)BATCH * 64 * 2);
    bf16_t* u3    = (bf16_t*)alloc((size_t)BATCH * 256 * 2);
    bf16_t* xcat  = (bf16_t*)alloc((size_t)BATCH * 384 * 2);
    bf16_t* f1    = (bf16_t*)alloc((size_t)BATCH * 128 * 2);
    bf16_t* f2    = (bf16_t*)alloc((size_t)BATCH * 64 * 2);

    // ---- CSR build ----
    hipMemsetAsync(hist, 0, NSEG * 4, stream);
    hipMemsetAsync(cursor, 0, NSEG * 4, stream);
    hist_kernel<<<(N_EDGES + 255) / 256, 256, 0, stream>>>(edge_dst, edge_rel, hist);
    int nscan = (NSEG + SCAN_B - 1) / SCAN_B;
    scan1<<<nscan, 256, 0, stream>>>(hist, offs, bsums, NSEG);
    scan2<<<1, 64, 0, stream>>>(bsums, nscan);
    scan3<<<nscan, 256, 0, stream>>>(offs, bsums, NSEG);
    csr_fill<<<(N_EDGES + 255) / 256, 256, 0, stream>>>(edge_dst, edge_rel, offs, cursor, csre);

    // ---- weight prep + converts ----
    prep_w1cat<<<512, 256, 0, stream>>>(Wl1, We1, Ws1, be1, W1cat);
    prep_w2cat<<<128, 256, 0, stream>>>(Wl2, We2, Ws2, be2, W2cat);
    prep_w2p<<<(512 * 512) / 256, 256, 0, stream>>>(Wl2, W2p);
    f2bf4_k<<<(256 * 64 / 4 + 255) / 256, 256, 0, stream>>>(Wc1, Wc1b, 256 * 64 / 4);
    f2bf4_k<<<(128 * 256 / 4 + 255) / 256, 256, 0, stream>>>(Wc2, Wc2b, 128 * 256 / 4);
    f2bf4_k<<<(128 * 384 / 4 + 255) / 256, 256, 0, stream>>>(Wf1, Wf1b, 128 * 384 / 4);
    f2bf4_k<<<(64 * 128 / 4 + 255) / 256, 256, 0, stream>>>(Wf2, Wf2b, 64 * 128 / 4);
    addbias_k<<<2, 256, 0, stream>>>(bl1, bs1, bias12, 512);
    addbias_k<<<1, 256, 0, stream>>>(bl2, bs2, bias22, 128);
    f2bf4_k<<<((int)((size_t)N_EDGES * 64 / 4) + 255) / 256, 256, 0, stream>>>(edge_feature, efb, N_EDGES * 64 / 4);
    xconv_k<<<(N_NODES * 64 + 255) / 256, 256, 0, stream>>>(node_feature, A1);

    // ---- layer 1 ----
    agg1<<<N_NODES, 256, 0, stream>>>(efb, edge_src, offs, hist, csre, A1, A2);
    {   // h1 = relu(A1 @ W1cat^T + bias12) -> A2 cols 256..767
        dim3 g((N_NODES + 127) / 128, HID / 128);
        gemm_bf16<1, 0, 1><<<g, 256, 0, stream>>>(A1, K1, W1cat, K1, nullptr, 0, bias12,
                                                  A2 + 256, K2, N_NODES, HID, K1);
    }

    // ---- layer 2 ----
    {   // P = h1 @ W2p^T
        dim3 g((N_NODES + 127) / 128, HID / 128);
        gemm_bf16<0, 0, 1><<<g, 256, 0, stream>>>(A2 + 256, K2, W2p, 512, nullptr, 0, nullptr,
                                                  Pbuf, HID, N_NODES, HID, HID);
    }
    agg2<<<N_NODES, 256, 0, stream>>>(Pbuf, edge_src, offs, hist, csre, h2base);
    {   // h2 = relu(h2base + A2 @ W2cat^T + bias22)
        dim3 g((N_NODES + 127) / 128, 1);
        gemm_bf16<1, 1, 1><<<g, 256, 0, stream>>>(A2, K2, W2cat, K2, h2base, 128, bias22,
                                                  h2, 128, N_NODES, 128, K2);
    }

    // ---- head ----
    gather_head<<<BATCH, 256, 0, stream>>>(inputs, h2, efb, xcat, ef_g);
    {   // u3 = relu(ef_g @ Wc1^T + bc1)
        dim3 g(BATCH / 128, 2);
        gemm_bf16<1, 0, 1><<<g, 256, 0, stream>>>(ef_g, 64, Wc1b, 64, nullptr, 0, bc1,
                                                  u3, 256, BATCH, 256, 64);
    }
    {   // xcat[:,256:384] = u3 @ Wc2^T + bc2
        dim3 g(BATCH / 128, 1);
        gemm_bf16<0, 0, 1><<<g, 256, 0, stream>>>(u3, 256, Wc2b, 256, nullptr, 0, bc2,
                                                  xcat + 256, 384, BATCH, 128, 256);
    }
    {   // f1 = relu(xcat @ Wf1^T + bf1)
        dim3 g(BATCH / 128, 1);
        gemm_bf16<1, 0, 1><<<g, 256, 0, stream>>>(xcat, 384, Wf1b, 384, nullptr, 0, bf1,
                                                  f1, 128, BATCH, 128, 384);
    }
    {   // f2 = relu(f1 @ Wf2^T + bf2)
        dim3 g(BATCH / 128, 1);
        gemm_bf16<1, 0, 1><<<g, 256, 0, stream>>>(f1, 128, Wf2b, 128, nullptr, 0, bf2,
                                                  f2, 64, BATCH, 64, 128);
    }
    final_matvec<<<BATCH / 4, 256, 0, stream>>>(f2, Wf3, bf3, out, BATCH);
}

// Round 4
// 821.197 us; speedup vs baseline: 19.7724x; 1.2031x over previous
//
#include <hip/hip_runtime.h>
#include <hip/hip_bf16.h>

#define N_NODES 50000
#define N_EDGES 800000
#define NODE_DIM 256
#define EDGE_DIM 64
#define NUM_REL 4
#define HID 512
#define LAST 128
#define BATCH 16384
#define EPS 1e-10f
#define NSEG (N_NODES * NUM_REL)

#define K1 1568   // meanX 1024 | E1 256 | x 256 | f 4 | pad 28
#define K2 800    // E1 256 | h1 512 | f 4 | pad 28

typedef __bf16 bf16_t;
typedef __attribute__((ext_vector_type(8))) __bf16 bf16x8;
typedef __attribute__((ext_vector_type(4))) __bf16 bf16x4;
typedef __attribute__((ext_vector_type(2))) __bf16 bf16x2;
typedef __attribute__((ext_vector_type(4))) float f32x4;

typedef __attribute__((address_space(1))) const unsigned int g_u32;
typedef __attribute__((address_space(3))) unsigned int l_u32;
static __device__ __forceinline__ void gload16(const void* g, void* l) {
    __builtin_amdgcn_global_load_lds((g_u32*)g, (l_u32*)l, 16, 0, 0);
}

// ================= CSR build =================
__global__ __launch_bounds__(256) void hist_kernel(
    const int* __restrict__ edst, const int* __restrict__ erel, int* __restrict__ hist)
{
    int e = blockIdx.x * 256 + threadIdx.x;
    if (e >= N_EDGES) return;
    atomicAdd(&hist[edst[e] * NUM_REL + erel[e]], 1);
}

#define SCAN_B 2048
__global__ __launch_bounds__(256) void scan1(
    const int* __restrict__ in, int* __restrict__ out, int* __restrict__ bsum, int n)
{
    __shared__ int sh[256];
    int base = blockIdx.x * SCAN_B + threadIdx.x * 8;
    int v[8]; int s = 0;
#pragma unroll
    for (int i = 0; i < 8; ++i) {
        int idx = base + i;
        v[i] = s;
        s += (idx < n) ? in[idx] : 0;
    }
    sh[threadIdx.x] = s;
    __syncthreads();
    for (int off = 1; off < 256; off <<= 1) {
        int t = (threadIdx.x >= off) ? sh[threadIdx.x - off] : 0;
        __syncthreads();
        sh[threadIdx.x] += t;
        __syncthreads();
    }
    int texcl = (threadIdx.x == 0) ? 0 : sh[threadIdx.x - 1];
#pragma unroll
    for (int i = 0; i < 8; ++i) {
        int idx = base + i;
        if (idx < n) out[idx] = texcl + v[i];
    }
    if (threadIdx.x == 255) bsum[blockIdx.x] = sh[255];
}

__global__ void scan2(int* bsum, int nb)
{
    if (threadIdx.x == 0 && blockIdx.x == 0) {
        int s = 0;
        for (int i = 0; i < nb; ++i) { int t = bsum[i]; bsum[i] = s; s += t; }
    }
}

__global__ __launch_bounds__(256) void scan3(int* __restrict__ out, const int* __restrict__ bsum, int n)
{
    int idx = blockIdx.x * SCAN_B + threadIdx.x * 8;
    int add = bsum[blockIdx.x];
#pragma unroll
    for (int i = 0; i < 8; ++i)
        if (idx + i < n) out[idx + i] += add;
}

__global__ __launch_bounds__(256) void csr_fill(
    const int* __restrict__ edst, const int* __restrict__ erel, const int* __restrict__ esrc,
    const int* __restrict__ offs, int* __restrict__ cursor,
    int* __restrict__ csr_src, int* __restrict__ csr_eid)
{
    int e = blockIdx.x * 256 + threadIdx.x;
    if (e >= N_EDGES) return;
    int seg = edst[e] * NUM_REL + erel[e];
    int pos = offs[seg] + atomicAdd(&cursor[seg], 1);
    csr_src[pos] = esrc[e];
    csr_eid[pos] = e;
}

// ================= converts =================
__global__ __launch_bounds__(256) void f2bf4_k(const float* __restrict__ src, bf16_t* __restrict__ dst, int n4)
{
    int i = blockIdx.x * 256 + threadIdx.x;
    if (i >= n4) return;
    float4 v = ((const float4*)src)[i];
    bf16x4 o;
    o[0] = (bf16_t)v.x; o[1] = (bf16_t)v.y; o[2] = (bf16_t)v.z; o[3] = (bf16_t)v.w;
    ((bf16x4*)dst)[i] = o;
}

__global__ __launch_bounds__(256) void addbias_k(const float* __restrict__ a, const float* __restrict__ b,
                                                 float* __restrict__ o, int n)
{
    int i = blockIdx.x * 256 + threadIdx.x;
    if (i < n) o[i] = a[i] + b[i];
}

// x (fp32 [50000,256]) -> A1 cols 1280..1535 (bf16) AND compact xb [50000,256]
__global__ __launch_bounds__(256) void xconv_k(const float* __restrict__ x, bf16_t* __restrict__ A1,
                                               bf16_t* __restrict__ xb)
{
    int i = blockIdx.x * 256 + threadIdx.x;   // over 50000*64
    int n = i >> 6;
    int c4 = i & 63;
    float4 v = ((const float4*)(x + (size_t)n * 256))[c4];
    bf16x4 o;
    o[0] = (bf16_t)v.x; o[1] = (bf16_t)v.y; o[2] = (bf16_t)v.z; o[3] = (bf16_t)v.w;
    *(bf16x4*)(A1 + (size_t)n * K1 + 1280 + c4 * 4) = o;
    *(bf16x4*)(xb + (size_t)n * 256 + c4 * 4) = o;
}

// ================= weight prep =================
__global__ __launch_bounds__(256) void prep_w1cat(
    const float* __restrict__ Wl1, const float* __restrict__ We1,
    const float* __restrict__ Ws1, const float* __restrict__ be1, bf16_t* __restrict__ W1cat)
{
    int j = blockIdx.x;
    int t = threadIdx.x;
    const float* wrow = Wl1 + (size_t)j * 1024;
    bf16_t* out = W1cat + (size_t)j * K1;
    for (int c = t; c < 1024; c += 256) out[c] = (bf16_t)wrow[c];
    {
        int r = t >> 6, e = t & 63;
        float s = 0.f;
        const float* wr = wrow + r * 256;
        for (int c = 0; c < 256; ++c) s += wr[c] * We1[c * 64 + e];
        out[1024 + t] = (bf16_t)s;
    }
    if (t < 256) out[1280 + t] = (bf16_t)Ws1[(size_t)j * 256 + t];
    if (t < 4) {
        float s = 0.f;
        const float* wr = wrow + t * 256;
        for (int c = 0; c < 256; ++c) s += wr[c] * be1[c];
        out[1536 + t] = (bf16_t)s;
    }
    if (t >= 4 && t < 32) out[1536 + t] = (bf16_t)0.f;
}

__global__ __launch_bounds__(256) void prep_w2cat(
    const float* __restrict__ Wl2, const float* __restrict__ We2,
    const float* __restrict__ Ws2, const float* __restrict__ be2, bf16_t* __restrict__ W2cat)
{
    int j = blockIdx.x;
    int t = threadIdx.x;
    const float* wrow = Wl2 + (size_t)j * 2048;
    bf16_t* out = W2cat + (size_t)j * K2;
    {
        int r = t >> 6, e = t & 63;
        float s = 0.f;
        const float* wr = wrow + r * 512;
        for (int k = 0; k < 512; ++k) s += wr[k] * We2[k * 64 + e];
        out[t] = (bf16_t)s;
    }
    for (int c = t; c < 512; c += 256) out[256 + c] = (bf16_t)Ws2[(size_t)j * 512 + c];
    if (t < 4) {
        float s = 0.f;
        const float* wr = wrow + t * 512;
        for (int k = 0; k < 512; ++k) s += wr[k] * be2[k];
        out[768 + t] = (bf16_t)s;
    }
    if (t >= 4 && t < 32) out[768 + t] = (bf16_t)0.f;
}

__global__ __launch_bounds__(256) void prep_w2p(const float* __restrict__ Wl2, bf16_t* __restrict__ W2p)
{
    int idx = blockIdx.x * 256 + threadIdx.x;    // 512*512
    int row = idx >> 9, k = idx & 511;
    int j = row & 127, r = row >> 7;
    W2p[idx] = (bf16_t)Wl2[(size_t)j * 2048 + r * 512 + k];
}

// ================= aggregation =================
// block = node n; wave w = relation r; 4x-unrolled independent gathers.
__global__ __launch_bounds__(256) void agg1(
    const float* __restrict__ ef, const bf16_t* __restrict__ xb,
    const int* __restrict__ csr_src, const int* __restrict__ csr_eid,
    const int* __restrict__ offs, const int* __restrict__ hist,
    bf16_t* __restrict__ A1, bf16_t* __restrict__ A2)
{
    int n = blockIdx.x;
    int w = threadIdx.x >> 6;
    int lane = threadIdx.x & 63;
    int seg = n * NUM_REL + w;
    int beg = offs[seg], ct = hist[seg];
    float a0 = 0.f, a1 = 0.f, a2 = 0.f, a3 = 0.f, aef = 0.f;
    int i = 0;
    for (; i + 4 <= ct; i += 4) {
        int s0 = csr_src[beg + i], s1 = csr_src[beg + i + 1];
        int s2 = csr_src[beg + i + 2], s3 = csr_src[beg + i + 3];
        int e0 = csr_eid[beg + i], e1 = csr_eid[beg + i + 1];
        int e2 = csr_eid[beg + i + 2], e3 = csr_eid[beg + i + 3];
        bf16x4 v0 = *(const bf16x4*)(xb + (size_t)s0 * 256 + lane * 4);
        bf16x4 v1 = *(const bf16x4*)(xb + (size_t)s1 * 256 + lane * 4);
        bf16x4 v2 = *(const bf16x4*)(xb + (size_t)s2 * 256 + lane * 4);
        bf16x4 v3 = *(const bf16x4*)(xb + (size_t)s3 * 256 + lane * 4);
        float f0 = ef[(size_t)e0 * 64 + lane];
        float f1 = ef[(size_t)e1 * 64 + lane];
        float f2 = ef[(size_t)e2 * 64 + lane];
        float f3 = ef[(size_t)e3 * 64 + lane];
        a0 += (float)v0[0] + (float)v1[0] + (float)v2[0] + (float)v3[0];
        a1 += (float)v0[1] + (float)v1[1] + (float)v2[1] + (float)v3[1];
        a2 += (float)v0[2] + (float)v1[2] + (float)v2[2] + (float)v3[2];
        a3 += (float)v0[3] + (float)v1[3] + (float)v2[3] + (float)v3[3];
        aef += f0 + f1 + f2 + f3;
    }
    for (; i < ct; ++i) {
        int s0 = csr_src[beg + i];
        int e0 = csr_eid[beg + i];
        bf16x4 v0 = *(const bf16x4*)(xb + (size_t)s0 * 256 + lane * 4);
        a0 += (float)v0[0]; a1 += (float)v0[1]; a2 += (float)v0[2]; a3 += (float)v0[3];
        aef += ef[(size_t)e0 * 64 + lane];
    }
    float inv = 1.0f / ((float)ct + EPS);
    bf16x4 m;
    m[0] = (bf16_t)(a0 * inv); m[1] = (bf16_t)(a1 * inv);
    m[2] = (bf16_t)(a2 * inv); m[3] = (bf16_t)(a3 * inv);
    *(bf16x4*)(A1 + (size_t)n * K1 + w * 256 + lane * 4) = m;
    bf16_t ev = (bf16_t)(aef * inv);
    A1[(size_t)n * K1 + 1024 + w * 64 + lane] = ev;
    A2[(size_t)n * K2 + w * 64 + lane] = ev;
    if (lane == 0) {
        bf16_t fv = (bf16_t)((float)ct * inv);
        A1[(size_t)n * K1 + 1536 + w] = fv;
        A2[(size_t)n * K2 + 768 + w] = fv;
    }
    if (w == 3) {
        if (lane >= 4 && lane < 32)  A1[(size_t)n * K1 + 1536 + lane] = (bf16_t)0.f;
        if (lane >= 36 && lane < 64) A2[(size_t)n * K2 + 772 + (lane - 36)] = (bf16_t)0.f;
    }
}

// block = node n; wave w = relation r; sum P[src, r*128:...] -> mean; cross-wave reduce
__global__ __launch_bounds__(256) void agg2(
    const bf16_t* __restrict__ P, const int* __restrict__ csr_src,
    const int* __restrict__ offs, const int* __restrict__ hist,
    float* __restrict__ h2base)
{
    __shared__ float red[4][128];
    int n = blockIdx.x;
    int w = threadIdx.x >> 6;
    int lane = threadIdx.x & 63;
    int seg = n * NUM_REL + w;
    int beg = offs[seg], ct = hist[seg];
    float s0 = 0.f, s1 = 0.f;
    int i = 0;
    for (; i + 4 <= ct; i += 4) {
        int a = csr_src[beg + i], b = csr_src[beg + i + 1];
        int c = csr_src[beg + i + 2], d = csr_src[beg + i + 3];
        bf16x2 va = *(const bf16x2*)(P + (size_t)a * HID + w * 128 + lane * 2);
        bf16x2 vb = *(const bf16x2*)(P + (size_t)b * HID + w * 128 + lane * 2);
        bf16x2 vc = *(const bf16x2*)(P + (size_t)c * HID + w * 128 + lane * 2);
        bf16x2 vd = *(const bf16x2*)(P + (size_t)d * HID + w * 128 + lane * 2);
        s0 += (float)va[0] + (float)vb[0] + (float)vc[0] + (float)vd[0];
        s1 += (float)va[1] + (float)vb[1] + (float)vc[1] + (float)vd[1];
    }
    for (; i < ct; ++i) {
        int a = csr_src[beg + i];
        bf16x2 va = *(const bf16x2*)(P + (size_t)a * HID + w * 128 + lane * 2);
        s0 += (float)va[0]; s1 += (float)va[1];
    }
    float inv = 1.0f / ((float)ct + EPS);
    red[w][lane * 2] = s0 * inv;
    red[w][lane * 2 + 1] = s1 * inv;
    __syncthreads();
    int t = threadIdx.x;
    if (t < 128)
        h2base[(size_t)n * 128 + t] = red[0][t] + red[1][t] + red[2][t] + red[3][t];
}

// ================= bf16 MFMA GEMM (m97 structure) =================
// C = act(A[M,K]@W[N,K]^T + bias [+ Cin]); 128x128 tile, BK=32, linear LDS,
// global_load_lds width-16 staging, 2 barriers per K-step.
template<int RELU, int ACC, int OUTBF>
__global__ __launch_bounds__(256) void gemm_bf16(
    const bf16_t* __restrict__ A, int lda,
    const bf16_t* __restrict__ W, int ldw,
    const float* __restrict__ Cin, int ldcin,
    const float* __restrict__ bias,
    void* __restrict__ Cout, int ldc,
    int M, int N, int K)
{
    __shared__ char smem[16384];
    char* As = smem;           // [128][64B] linear
    char* Bs = smem + 8192;
    const int tid = threadIdx.x;
    const int row0 = blockIdx.x * 128;
    const int col0 = blockIdx.y * 128;
    const int lane = tid & 63, wv = tid >> 6;

    // staging: wave wv stages A rows wv*32..wv*32+31 and B rows likewise.
    // instr q in {0,1}: lane l -> row wv*32 + q*16 + (l>>2), chunk l&3 (8 bf16)
    const int srow = wv * 32 + (lane >> 2);
    const int schunk = (lane & 3) * 8;
    int ga0 = row0 + srow;      if (ga0 >= M) ga0 = M - 1;
    int ga1 = row0 + srow + 16; if (ga1 >= M) ga1 = M - 1;
    int gb0 = col0 + srow;      if (gb0 >= N) gb0 = N - 1;
    int gb1 = col0 + srow + 16; if (gb1 >= N) gb1 = N - 1;
    const bf16_t* pa0 = A + (size_t)ga0 * lda + schunk;
    const bf16_t* pa1 = A + (size_t)ga1 * lda + schunk;
    const bf16_t* pb0 = W + (size_t)gb0 * ldw + schunk;
    const bf16_t* pb1 = W + (size_t)gb1 * ldw + schunk;
    char* lA0 = As + wv * 2048;
    char* lA1 = As + wv * 2048 + 1024;
    char* lB0 = Bs + wv * 2048;
    char* lB1 = Bs + wv * 2048 + 1024;

    // compute addressing: wave quadrant (wm, wn)
    const int wm = wv >> 1, wn = wv & 1;
    const int r16 = lane & 15, kch = lane >> 4;

    f32x4 zero = {0.f, 0.f, 0.f, 0.f};
    f32x4 acc[4][4];
#pragma unroll
    for (int i = 0; i < 4; ++i)
#pragma unroll
        for (int j = 0; j < 4; ++j) acc[i][j] = zero;

    for (int k0 = 0; k0 < K; k0 += 32) {
        gload16(pa0 + k0, lA0);
        gload16(pa1 + k0, lA1);
        gload16(pb0 + k0, lB0);
        gload16(pb1 + k0, lB1);
        __syncthreads();
        bf16x8 af[4], bfm[4];
#pragma unroll
        for (int i = 0; i < 4; ++i)
            af[i] = *(const bf16x8*)(As + (wm * 64 + i * 16 + r16) * 64 + kch * 16);
#pragma unroll
        for (int j = 0; j < 4; ++j)
            bfm[j] = *(const bf16x8*)(Bs + (wn * 64 + j * 16 + r16) * 64 + kch * 16);
#pragma unroll
        for (int i = 0; i < 4; ++i)
#pragma unroll
            for (int j = 0; j < 4; ++j)
                acc[i][j] = __builtin_amdgcn_mfma_f32_16x16x32_bf16(af[i], bfm[j], acc[i][j], 0, 0, 0);
        __syncthreads();
    }

    const int crow0 = row0 + wm * 64;
#pragma unroll
    for (int i = 0; i < 4; ++i) {
#pragma unroll
        for (int j = 0; j < 4; ++j) {
            int col = col0 + wn * 64 + j * 16 + r16;
            if (col >= N) continue;
            float bv = bias ? bias[col] : 0.f;
#pragma unroll
            for (int q = 0; q < 4; ++q) {
                int row = crow0 + i * 16 + kch * 4 + q;
                if (row >= M) continue;
                float v = acc[i][j][q] + bv;
                if (ACC) v += Cin[(size_t)row * ldcin + col];
                if (RELU) v = fmaxf(v, 0.f);
                if (OUTBF) ((bf16_t*)Cout)[(size_t)row * ldc + col] = (bf16_t)v;
                else       ((float*)Cout)[(size_t)row * ldc + col] = v;
            }
        }
    }
}

// ================= head =================
__global__ __launch_bounds__(256) void gather_head(
    const int* __restrict__ inputs, const bf16_t* __restrict__ h2,
    const float* __restrict__ ef, bf16_t* __restrict__ xcat, bf16_t* __restrict__ ef_g)
{
    int i = blockIdx.x;
    int t = threadIdx.x;
    int d1 = inputs[i * 3 + 0];
    int d2 = inputs[i * 3 + 1];
    int ctx = inputs[i * 3 + 2];
    if (t < 128) {
        xcat[(size_t)i * 384 + t] = h2[(size_t)d1 * LAST + t];
    } else {
        int c = t - 128;
        xcat[(size_t)i * 384 + 128 + c] = h2[(size_t)d2 * LAST + c];
    }
    if (t < 64) ef_g[(size_t)i * 64 + t] = (bf16_t)ef[(size_t)ctx * EDGE_DIM + t];
}

__global__ __launch_bounds__(256) void final_matvec(
    const bf16_t* __restrict__ f2, const float* __restrict__ Wf3,
    const float* __restrict__ bf3, float* __restrict__ out, int M)
{
    int row = blockIdx.x * 4 + (threadIdx.x >> 6);
    int lane = threadIdx.x & 63;
    if (row >= M) return;
    float v = (float)f2[(size_t)row * 64 + lane] * Wf3[lane];
#pragma unroll
    for (int off = 32; off > 0; off >>= 1) v += __shfl_down(v, off);
    if (lane == 0) out[row] = v + bf3[0];
}

extern "C" void kernel_launch(void* const* d_in, const int* in_sizes, int n_in,
                              void* d_out, int out_size, void* d_ws, size_t ws_size,
                              hipStream_t stream)
{
    const int*   inputs       = (const int*)  d_in[0];
    const float* node_feature = (const float*)d_in[1];
    const float* edge_feature = (const float*)d_in[2];
    const int*   edge_src     = (const int*)  d_in[3];
    const int*   edge_dst     = (const int*)  d_in[4];
    const int*   edge_rel     = (const int*)  d_in[5];
    const float* We1 = (const float*)d_in[6];
    const float* be1 = (const float*)d_in[7];
    const float* Wl1 = (const float*)d_in[8];
    const float* bl1 = (const float*)d_in[9];
    const float* Ws1 = (const float*)d_in[10];
    const float* bs1 = (const float*)d_in[11];
    const float* We2 = (const float*)d_in[12];
    const float* be2 = (const float*)d_in[13];
    const float* Wl2 = (const float*)d_in[14];
    const float* bl2 = (const float*)d_in[15];
    const float* Ws2 = (const float*)d_in[16];
    const float* bs2 = (const float*)d_in[17];
    const float* Wc1 = (const float*)d_in[18];
    const float* bc1 = (const float*)d_in[19];
    const float* Wc2 = (const float*)d_in[20];
    const float* bc2 = (const float*)d_in[21];
    const float* Wf1 = (const float*)d_in[22];
    const float* bf1 = (const float*)d_in[23];
    const float* Wf2 = (const float*)d_in[24];
    const float* bf2 = (const float*)d_in[25];
    const float* Wf3 = (const float*)d_in[26];
    const float* bf3 = (const float*)d_in[27];
    float* out = (float*)d_out;

    // ---- workspace layout (256B aligned chunks) ----
    char* p = (char*)d_ws;
    auto alloc = [&](size_t bytes) { char* r = p; p += (bytes + 255) & ~(size_t)255; return r; };
    int* hist     = (int*)alloc(NSEG * 4);
    int* offs     = (int*)alloc(NSEG * 4);
    int* cursor   = (int*)alloc(NSEG * 4);
    int* csr_src  = (int*)alloc(N_EDGES * 4);
    int* csr_eid  = (int*)alloc(N_EDGES * 4);
    int* bsums    = (int*)alloc(128 * 4);
    bf16_t* A1    = (bf16_t*)alloc((size_t)N_NODES * K1 * 2);
    bf16_t* A2    = (bf16_t*)alloc((size_t)N_NODES * K2 * 2);
    bf16_t* xb    = (bf16_t*)alloc((size_t)N_NODES * 256 * 2);
    bf16_t* Pbuf  = (bf16_t*)alloc((size_t)N_NODES * HID * 2);
    float*  h2base= (float*)alloc((size_t)N_NODES * 128 * 4);
    bf16_t* h2    = (bf16_t*)alloc((size_t)N_NODES * 128 * 2);
    bf16_t* W1cat = (bf16_t*)alloc((size_t)512 * K1 * 2);
    bf16_t* W2cat = (bf16_t*)alloc((size_t)128 * K2 * 2);
    bf16_t* W2p   = (bf16_t*)alloc((size_t)512 * 512 * 2);
    bf16_t* Wc1b  = (bf16_t*)alloc(256 * 64 * 2);
    bf16_t* Wc2b  = (bf16_t*)alloc(128 * 256 * 2);
    bf16_t* Wf1b  = (bf16_t*)alloc(128 * 384 * 2);
    bf16_t* Wf2b  = (bf16_t*)alloc(64 * 128 * 2);
    float*  bias12= (float*)alloc(512 * 4);
    float*  bias22= (float*)alloc(128 * 4);
    bf16_t* ef_g  = (bf16_t*)alloc((size_t)BATCH * 64 * 2);
    bf16_t* u3    = (bf16_t*)alloc((size_t)BATCH * 256 * 2);
    bf16_t* xcat  = (bf16_t*)alloc((size_t)BATCH * 384 * 2);
    bf16_t* f1    = (bf16_t*)alloc((size_t)BATCH * 128 * 2);
    bf16_t* f2    = (bf16_t*)alloc((size_t)BATCH * 64 * 2);

    // ---- CSR build ----
    hipMemsetAsync(hist, 0, NSEG * 4, stream);
    hipMemsetAsync(cursor, 0, NSEG * 4, stream);
    hist_kernel<<<(N_EDGES + 255) / 256, 256, 0, stream>>>(edge_dst, edge_rel, hist);
    int nscan = (NSEG + SCAN_B - 1) / SCAN_B;
    scan1<<<nscan, 256, 0, stream>>>(hist, offs, bsums, NSEG);
    scan2<<<1, 64, 0, stream>>>(bsums, nscan);
    scan3<<<nscan, 256, 0, stream>>>(offs, bsums, NSEG);
    csr_fill<<<(N_EDGES + 255) / 256, 256, 0, stream>>>(edge_dst, edge_rel, edge_src,
                                                        offs, cursor, csr_src, csr_eid);

    // ---- weight prep + converts ----
    prep_w1cat<<<512, 256, 0, stream>>>(Wl1, We1, Ws1, be1, W1cat);
    prep_w2cat<<<128, 256, 0, stream>>>(Wl2, We2, Ws2, be2, W2cat);
    prep_w2p<<<(512 * 512) / 256, 256, 0, stream>>>(Wl2, W2p);
    f2bf4_k<<<(256 * 64 / 4 + 255) / 256, 256, 0, stream>>>(Wc1, Wc1b, 256 * 64 / 4);
    f2bf4_k<<<(128 * 256 / 4 + 255) / 256, 256, 0, stream>>>(Wc2, Wc2b, 128 * 256 / 4);
    f2bf4_k<<<(128 * 384 / 4 + 255) / 256, 256, 0, stream>>>(Wf1, Wf1b, 128 * 384 / 4);
    f2bf4_k<<<(64 * 128 / 4 + 255) / 256, 256, 0, stream>>>(Wf2, Wf2b, 64 * 128 / 4);
    addbias_k<<<2, 256, 0, stream>>>(bl1, bs1, bias12, 512);
    addbias_k<<<1, 256, 0, stream>>>(bl2, bs2, bias22, 128);
    xconv_k<<<(N_NODES * 64 + 255) / 256, 256, 0, stream>>>(node_feature, A1, xb);

    // ---- layer 1 ----
    agg1<<<N_NODES, 256, 0, stream>>>(edge_feature, xb, csr_src, csr_eid, offs, hist, A1, A2);
    {   // h1 = relu(A1 @ W1cat^T + bias12) -> A2 cols 256..767
        dim3 g((N_NODES + 127) / 128, HID / 128);
        gemm_bf16<1, 0, 1><<<g, 256, 0, stream>>>(A1, K1, W1cat, K1, nullptr, 0, bias12,
                                                  A2 + 256, K2, N_NODES, HID, K1);
    }

    // ---- layer 2 ----
    {   // P = h1 @ W2p^T
        dim3 g((N_NODES + 127) / 128, HID / 128);
        gemm_bf16<0, 0, 1><<<g, 256, 0, stream>>>(A2 + 256, K2, W2p, 512, nullptr, 0, nullptr,
                                                  Pbuf, HID, N_NODES, HID, HID);
    }
    agg2<<<N_NODES, 256, 0, stream>>>(Pbuf, csr_src, offs, hist, h2base);
    {   // h2 = relu(h2base + A2 @ W2cat^T + bias22)
        dim3 g((N_NODES + 127) / 128, 1);
        gemm_bf16<1, 1, 1><<<g, 256, 0, stream>>>(A2, K2, W2cat, K2, h2base, 128, bias22,
                                                  h2, 128, N_NODES, 128, K2);
    }

    // ---- head ----
    gather_head<<<BATCH, 256, 0, stream>>>(inputs, h2, edge_feature, xcat, ef_g);
    {   // u3 = relu(ef_g @ Wc1^T + bc1)
        dim3 g(BATCH / 128, 2);
        gemm_bf16<1, 0, 1><<<g, 256, 0, stream>>>(ef_g, 64, Wc1b, 64, nullptr, 0, bc1,
                                                  u3, 256, BATCH, 256, 64);
    }
    {   // xcat[:,256:384] = u3 @ Wc2^T + bc2
        dim3 g(BATCH / 128, 1);
        gemm_bf16<0, 0, 1><<<g, 256, 0, stream>>>(u3, 256, Wc2b, 256, nullptr, 0, bc2,
                                                  xcat + 256, 384, BATCH, 128, 256);
    }
    {   // f1 = relu(xcat @ Wf1^T + bf1)
        dim3 g(BATCH / 128, 1);
        gemm_bf16<1, 0, 1><<<g, 256, 0, stream>>>(xcat, 384, Wf1b, 384, nullptr, 0, bf1,
                                                  f1, 128, BATCH, 128, 384);
    }
    {   // f2 = relu(f1 @ Wf2^T + bf2)
        dim3 g(BATCH / 128, 1);
        gemm_bf16<1, 0, 1><<<g, 256, 0, stream>>>(f1, 128, Wf2b, 128, nullptr, 0, bf2,
                                                  f2, 64, BATCH, 64, 128);
    }
    final_matvec<<<BATCH / 4, 256, 0, stream>>>(f2, Wf3, bf3, out, BATCH);
}

// Round 5
// 750.198 us; speedup vs baseline: 21.6437x; 1.0946x over previous
//
#include <hip/hip_runtime.h>
#include <hip/hip_bf16.h>

#define N_NODES 50000
#define N_EDGES 800000
#define NODE_DIM 256
#define EDGE_DIM 64
#define NUM_REL 4
#define HID 512
#define LAST 128
#define BATCH 16384
#define EPS 1e-10f
#define NSEG (N_NODES * NUM_REL)

#define K1 1600   // meanX 1024 | E1 256 | x 256 | f 4 | pad 60
#define K2 832    // E1 256 | h1 512 | f 4 | pad 60

typedef __bf16 bf16_t;
typedef __attribute__((ext_vector_type(8))) __bf16 bf16x8;
typedef __attribute__((ext_vector_type(4))) __bf16 bf16x4;
typedef __attribute__((ext_vector_type(2))) __bf16 bf16x2;
typedef __attribute__((ext_vector_type(4))) float f32x4;

typedef __attribute__((address_space(1))) const unsigned int g_u32;
typedef __attribute__((address_space(3))) unsigned int l_u32;
static __device__ __forceinline__ void gload16(const void* g, void* l) {
    __builtin_amdgcn_global_load_lds((g_u32*)g, (l_u32*)l, 16, 0, 0);
}

// ================= CSR build =================
__global__ __launch_bounds__(256) void hist_kernel(
    const int* __restrict__ edst, const int* __restrict__ erel, int* __restrict__ hist)
{
    int e = blockIdx.x * 256 + threadIdx.x;
    if (e >= N_EDGES) return;
    atomicAdd(&hist[edst[e] * NUM_REL + erel[e]], 1);
}

#define SCAN_B 2048
__global__ __launch_bounds__(256) void scan1(
    const int* __restrict__ in, int* __restrict__ out, int* __restrict__ bsum, int n)
{
    __shared__ int sh[256];
    int base = blockIdx.x * SCAN_B + threadIdx.x * 8;
    int v[8]; int s = 0;
#pragma unroll
    for (int i = 0; i < 8; ++i) {
        int idx = base + i;
        v[i] = s;
        s += (idx < n) ? in[idx] : 0;
    }
    sh[threadIdx.x] = s;
    __syncthreads();
    for (int off = 1; off < 256; off <<= 1) {
        int t = (threadIdx.x >= off) ? sh[threadIdx.x - off] : 0;
        __syncthreads();
        sh[threadIdx.x] += t;
        __syncthreads();
    }
    int texcl = (threadIdx.x == 0) ? 0 : sh[threadIdx.x - 1];
#pragma unroll
    for (int i = 0; i < 8; ++i) {
        int idx = base + i;
        if (idx < n) out[idx] = texcl + v[i];
    }
    if (threadIdx.x == 255) bsum[blockIdx.x] = sh[255];
}

__global__ void scan2(int* bsum, int nb)
{
    if (threadIdx.x == 0 && blockIdx.x == 0) {
        int s = 0;
        for (int i = 0; i < nb; ++i) { int t = bsum[i]; bsum[i] = s; s += t; }
    }
}

__global__ __launch_bounds__(256) void scan3(int* __restrict__ out, const int* __restrict__ bsum, int n)
{
    int idx = blockIdx.x * SCAN_B + threadIdx.x * 8;
    int add = bsum[blockIdx.x];
#pragma unroll
    for (int i = 0; i < 8; ++i)
        if (idx + i < n) out[idx + i] += add;
}

__global__ __launch_bounds__(256) void csr_fill(
    const int* __restrict__ edst, const int* __restrict__ erel, const int* __restrict__ esrc,
    const int* __restrict__ offs, int* __restrict__ cursor,
    int* __restrict__ csr_src, int* __restrict__ csr_eid)
{
    int e = blockIdx.x * 256 + threadIdx.x;
    if (e >= N_EDGES) return;
    int seg = edst[e] * NUM_REL + erel[e];
    int pos = offs[seg] + atomicAdd(&cursor[seg], 1);
    csr_src[pos] = esrc[e];
    csr_eid[pos] = e;
}

// ================= converts =================
__global__ __launch_bounds__(256) void f2bf4_k(const float* __restrict__ src, bf16_t* __restrict__ dst, int n4)
{
    int i = blockIdx.x * 256 + threadIdx.x;
    if (i >= n4) return;
    float4 v = ((const float4*)src)[i];
    bf16x4 o;
    o[0] = (bf16_t)v.x; o[1] = (bf16_t)v.y; o[2] = (bf16_t)v.z; o[3] = (bf16_t)v.w;
    ((bf16x4*)dst)[i] = o;
}

__global__ __launch_bounds__(256) void addbias_k(const float* __restrict__ a, const float* __restrict__ b,
                                                 float* __restrict__ o, int n)
{
    int i = blockIdx.x * 256 + threadIdx.x;
    if (i < n) o[i] = a[i] + b[i];
}

// x (fp32 [50000,256]) -> A1 cols 1280..1535 (bf16) AND compact xb [50000,256]
__global__ __launch_bounds__(256) void xconv_k(const float* __restrict__ x, bf16_t* __restrict__ A1,
                                               bf16_t* __restrict__ xb)
{
    int i = blockIdx.x * 256 + threadIdx.x;   // over 50000*64
    int n = i >> 6;
    int c4 = i & 63;
    float4 v = ((const float4*)(x + (size_t)n * 256))[c4];
    bf16x4 o;
    o[0] = (bf16_t)v.x; o[1] = (bf16_t)v.y; o[2] = (bf16_t)v.z; o[3] = (bf16_t)v.w;
    *(bf16x4*)(A1 + (size_t)n * K1 + 1280 + c4 * 4) = o;
    *(bf16x4*)(xb + (size_t)n * 256 + c4 * 4) = o;
}

// ================= weight prep =================
__global__ __launch_bounds__(256) void prep_w1cat(
    const float* __restrict__ Wl1, const float* __restrict__ We1,
    const float* __restrict__ Ws1, const float* __restrict__ be1, bf16_t* __restrict__ W1cat)
{
    int j = blockIdx.x;
    int t = threadIdx.x;
    const float* wrow = Wl1 + (size_t)j * 1024;
    bf16_t* out = W1cat + (size_t)j * K1;
    for (int c = t; c < 1024; c += 256) out[c] = (bf16_t)wrow[c];
    {
        int r = t >> 6, e = t & 63;
        float s = 0.f;
        const float* wr = wrow + r * 256;
        for (int c = 0; c < 256; ++c) s += wr[c] * We1[c * 64 + e];
        out[1024 + t] = (bf16_t)s;
    }
    if (t < 256) out[1280 + t] = (bf16_t)Ws1[(size_t)j * 256 + t];
    if (t < 4) {
        float s = 0.f;
        const float* wr = wrow + t * 256;
        for (int c = 0; c < 256; ++c) s += wr[c] * be1[c];
        out[1536 + t] = (bf16_t)s;
    }
    if (t >= 4 && t < 64) out[1536 + t] = (bf16_t)0.f;   // pad to K1=1600
}

__global__ __launch_bounds__(256) void prep_w2cat(
    const float* __restrict__ Wl2, const float* __restrict__ We2,
    const float* __restrict__ Ws2, const float* __restrict__ be2, bf16_t* __restrict__ W2cat)
{
    int j = blockIdx.x;
    int t = threadIdx.x;
    const float* wrow = Wl2 + (size_t)j * 2048;
    bf16_t* out = W2cat + (size_t)j * K2;
    {
        int r = t >> 6, e = t & 63;
        float s = 0.f;
        const float* wr = wrow + r * 512;
        for (int k = 0; k < 512; ++k) s += wr[k] * We2[k * 64 + e];
        out[t] = (bf16_t)s;
    }
    for (int c = t; c < 512; c += 256) out[256 + c] = (bf16_t)Ws2[(size_t)j * 512 + c];
    if (t < 4) {
        float s = 0.f;
        const float* wr = wrow + t * 512;
        for (int k = 0; k < 512; ++k) s += wr[k] * be2[k];
        out[768 + t] = (bf16_t)s;
    }
    if (t >= 4 && t < 64) out[768 + t] = (bf16_t)0.f;    // pad to K2=832
}

__global__ __launch_bounds__(256) void prep_w2p(const float* __restrict__ Wl2, bf16_t* __restrict__ W2p)
{
    int idx = blockIdx.x * 256 + threadIdx.x;    // 512*512
    int row = idx >> 9, k = idx & 511;
    int j = row & 127, r = row >> 7;
    W2p[idx] = (bf16_t)Wl2[(size_t)j * 2048 + r * 512 + k];
}

// ================= aggregation =================
__global__ __launch_bounds__(256) void agg1(
    const float* __restrict__ ef, const bf16_t* __restrict__ xb,
    const int* __restrict__ csr_src, const int* __restrict__ csr_eid,
    const int* __restrict__ offs, const int* __restrict__ hist,
    bf16_t* __restrict__ A1, bf16_t* __restrict__ A2)
{
    int n = blockIdx.x;
    int w = threadIdx.x >> 6;
    int lane = threadIdx.x & 63;
    int seg = n * NUM_REL + w;
    int beg = offs[seg], ct = hist[seg];
    float a0 = 0.f, a1 = 0.f, a2 = 0.f, a3 = 0.f, aef = 0.f;
    int i = 0;
    for (; i + 4 <= ct; i += 4) {
        int s0 = csr_src[beg + i], s1 = csr_src[beg + i + 1];
        int s2 = csr_src[beg + i + 2], s3 = csr_src[beg + i + 3];
        int e0 = csr_eid[beg + i], e1 = csr_eid[beg + i + 1];
        int e2 = csr_eid[beg + i + 2], e3 = csr_eid[beg + i + 3];
        bf16x4 v0 = *(const bf16x4*)(xb + (size_t)s0 * 256 + lane * 4);
        bf16x4 v1 = *(const bf16x4*)(xb + (size_t)s1 * 256 + lane * 4);
        bf16x4 v2 = *(const bf16x4*)(xb + (size_t)s2 * 256 + lane * 4);
        bf16x4 v3 = *(const bf16x4*)(xb + (size_t)s3 * 256 + lane * 4);
        float f0 = ef[(size_t)e0 * 64 + lane];
        float f1 = ef[(size_t)e1 * 64 + lane];
        float f2 = ef[(size_t)e2 * 64 + lane];
        float f3 = ef[(size_t)e3 * 64 + lane];
        a0 += (float)v0[0] + (float)v1[0] + (float)v2[0] + (float)v3[0];
        a1 += (float)v0[1] + (float)v1[1] + (float)v2[1] + (float)v3[1];
        a2 += (float)v0[2] + (float)v1[2] + (float)v2[2] + (float)v3[2];
        a3 += (float)v0[3] + (float)v1[3] + (float)v2[3] + (float)v3[3];
        aef += f0 + f1 + f2 + f3;
    }
    for (; i < ct; ++i) {
        int s0 = csr_src[beg + i];
        int e0 = csr_eid[beg + i];
        bf16x4 v0 = *(const bf16x4*)(xb + (size_t)s0 * 256 + lane * 4);
        a0 += (float)v0[0]; a1 += (float)v0[1]; a2 += (float)v0[2]; a3 += (float)v0[3];
        aef += ef[(size_t)e0 * 64 + lane];
    }
    float inv = 1.0f / ((float)ct + EPS);
    bf16x4 m;
    m[0] = (bf16_t)(a0 * inv); m[1] = (bf16_t)(a1 * inv);
    m[2] = (bf16_t)(a2 * inv); m[3] = (bf16_t)(a3 * inv);
    *(bf16x4*)(A1 + (size_t)n * K1 + w * 256 + lane * 4) = m;
    bf16_t ev = (bf16_t)(aef * inv);
    A1[(size_t)n * K1 + 1024 + w * 64 + lane] = ev;
    A2[(size_t)n * K2 + w * 64 + lane] = ev;
    if (lane == 0) {
        bf16_t fv = (bf16_t)((float)ct * inv);
        A1[(size_t)n * K1 + 1536 + w] = fv;
        A2[(size_t)n * K2 + 768 + w] = fv;
    }
    if (w == 3 && lane >= 4) {
        A1[(size_t)n * K1 + 1536 + lane] = (bf16_t)0.f;   // 1540..1599
        A2[(size_t)n * K2 + 768 + lane] = (bf16_t)0.f;    // 772..831
    }
}

__global__ __launch_bounds__(256) void agg2(
    const bf16_t* __restrict__ P, const int* __restrict__ csr_src,
    const int* __restrict__ offs, const int* __restrict__ hist,
    float* __restrict__ h2base)
{
    __shared__ float red[4][128];
    int n = blockIdx.x;
    int w = threadIdx.x >> 6;
    int lane = threadIdx.x & 63;
    int seg = n * NUM_REL + w;
    int beg = offs[seg], ct = hist[seg];
    float s0 = 0.f, s1 = 0.f;
    int i = 0;
    for (; i + 4 <= ct; i += 4) {
        int a = csr_src[beg + i], b = csr_src[beg + i + 1];
        int c = csr_src[beg + i + 2], d = csr_src[beg + i + 3];
        bf16x2 va = *(const bf16x2*)(P + (size_t)a * HID + w * 128 + lane * 2);
        bf16x2 vb = *(const bf16x2*)(P + (size_t)b * HID + w * 128 + lane * 2);
        bf16x2 vc = *(const bf16x2*)(P + (size_t)c * HID + w * 128 + lane * 2);
        bf16x2 vd = *(const bf16x2*)(P + (size_t)d * HID + w * 128 + lane * 2);
        s0 += (float)va[0] + (float)vb[0] + (float)vc[0] + (float)vd[0];
        s1 += (float)va[1] + (float)vb[1] + (float)vc[1] + (float)vd[1];
    }
    for (; i < ct; ++i) {
        int a = csr_src[beg + i];
        bf16x2 va = *(const bf16x2*)(P + (size_t)a * HID + w * 128 + lane * 2);
        s0 += (float)va[0]; s1 += (float)va[1];
    }
    float inv = 1.0f / ((float)ct + EPS);
    red[w][lane * 2] = s0 * inv;
    red[w][lane * 2 + 1] = s1 * inv;
    __syncthreads();
    int t = threadIdx.x;
    if (t < 128)
        h2base[(size_t)n * 128 + t] = red[0][t] + red[1][t] + red[2][t] + red[3][t];
}

// ================= bf16 MFMA GEMM =================
// C = act(A[M,K]@W[N,K]^T + bias [+ Cin]); 128x128 tile, BK=64, 4 waves.
// LDS rows are 128B, chunk slot = global_kchunk ^ (row&7): swizzle realized by
// permuting the per-lane GLOBAL source (linear gload_lds dest) + XOR on read.
// K must be a multiple of 64. Grid is 1D, column-fastest (col = bid % ncol).
template<int RELU, int ACC, int OUTBF>
__global__ __launch_bounds__(256) void gemm_bf16(
    const bf16_t* __restrict__ A, int lda,
    const bf16_t* __restrict__ W, int ldw,
    const float* __restrict__ Cin, int ldcin,
    const float* __restrict__ bias,
    void* __restrict__ Cout, int ldc,
    int M, int N, int K, int ncol)
{
    __shared__ char smem[32768];
    char* As = smem;            // [128 rows][8 slots][16B]
    char* Bs = smem + 16384;
    const int tid = threadIdx.x;
    const int row0 = (blockIdx.x / ncol) * 128;
    const int col0 = (blockIdx.x % ncol) * 128;
    const int lane = tid & 63, wv = tid >> 6;

    // staging: wave wv stages 8-row groups q = wv*4+s (s=0..3) of both A and B.
    // lane l -> row q*8 + (l>>3), stores global chunk ((l&7)^(l>>3)) at slot l&7.
    const int rsub = lane >> 3;
    const int gchunk = (lane & 7) ^ rsub;
    const bf16_t* pa[4]; const bf16_t* pb[4];
    char* la[4]; char* lb[4];
#pragma unroll
    for (int s = 0; s < 4; ++s) {
        int q = wv * 4 + s;
        int ar = row0 + q * 8 + rsub; if (ar >= M) ar = M - 1;
        int br = col0 + q * 8 + rsub; if (br >= N) br = N - 1;
        pa[s] = A + (size_t)ar * lda + gchunk * 8;
        pb[s] = W + (size_t)br * ldw + gchunk * 8;
        la[s] = As + q * 1024;
        lb[s] = Bs + q * 1024;
    }

    // compute addressing: wave quadrant (wm, wn)
    const int wm = wv >> 1, wn = wv & 1;
    const int r16 = lane & 15, kch = lane >> 4;
    const int sw = r16 & 7;

    f32x4 zero = {0.f, 0.f, 0.f, 0.f};
    f32x4 acc[4][4];
#pragma unroll
    for (int i = 0; i < 4; ++i)
#pragma unroll
        for (int j = 0; j < 4; ++j) acc[i][j] = zero;

    for (int k0 = 0; k0 < K; k0 += 64) {
#pragma unroll
        for (int s = 0; s < 4; ++s) {
            gload16(pa[s] + k0, la[s]);
            gload16(pb[s] + k0, lb[s]);
        }
        __syncthreads();
#pragma unroll
        for (int t = 0; t < 2; ++t) {
            const int slot = ((t * 4 + kch) ^ sw) << 4;
            bf16x8 af[4], bfm[4];
#pragma unroll
            for (int i = 0; i < 4; ++i)
                af[i] = *(const bf16x8*)(As + (wm * 64 + i * 16 + r16) * 128 + slot);
#pragma unroll
            for (int j = 0; j < 4; ++j)
                bfm[j] = *(const bf16x8*)(Bs + (wn * 64 + j * 16 + r16) * 128 + slot);
#pragma unroll
            for (int i = 0; i < 4; ++i)
#pragma unroll
                for (int j = 0; j < 4; ++j)
                    acc[i][j] = __builtin_amdgcn_mfma_f32_16x16x32_bf16(af[i], bfm[j], acc[i][j], 0, 0, 0);
        }
        __syncthreads();
    }

    const int crow0 = row0 + wm * 64;
#pragma unroll
    for (int i = 0; i < 4; ++i) {
#pragma unroll
        for (int j = 0; j < 4; ++j) {
            int col = col0 + wn * 64 + j * 16 + r16;
            if (col >= N) continue;
            float bv = bias ? bias[col] : 0.f;
#pragma unroll
            for (int q = 0; q < 4; ++q) {
                int row = crow0 + i * 16 + kch * 4 + q;
                if (row >= M) continue;
                float v = acc[i][j][q] + bv;
                if (ACC) v += Cin[(size_t)row * ldcin + col];
                if (RELU) v = fmaxf(v, 0.f);
                if (OUTBF) ((bf16_t*)Cout)[(size_t)row * ldc + col] = (bf16_t)v;
                else       ((float*)Cout)[(size_t)row * ldc + col] = v;
            }
        }
    }
}

// ================= head =================
__global__ __launch_bounds__(256) void gather_head(
    const int* __restrict__ inputs, const bf16_t* __restrict__ h2,
    const float* __restrict__ ef, bf16_t* __restrict__ xcat, bf16_t* __restrict__ ef_g)
{
    int i = blockIdx.x;
    int t = threadIdx.x;
    int d1 = inputs[i * 3 + 0];
    int d2 = inputs[i * 3 + 1];
    int ctx = inputs[i * 3 + 2];
    if (t < 128) {
        xcat[(size_t)i * 384 + t] = h2[(size_t)d1 * LAST + t];
    } else {
        int c = t - 128;
        xcat[(size_t)i * 384 + 128 + c] = h2[(size_t)d2 * LAST + c];
    }
    if (t < 64) ef_g[(size_t)i * 64 + t] = (bf16_t)ef[(size_t)ctx * EDGE_DIM + t];
}

__global__ __launch_bounds__(256) void final_matvec(
    const bf16_t* __restrict__ f2, const float* __restrict__ Wf3,
    const float* __restrict__ bf3, float* __restrict__ out, int M)
{
    int row = blockIdx.x * 4 + (threadIdx.x >> 6);
    int lane = threadIdx.x & 63;
    if (row >= M) return;
    float v = (float)f2[(size_t)row * 64 + lane] * Wf3[lane];
#pragma unroll
    for (int off = 32; off > 0; off >>= 1) v += __shfl_down(v, off);
    if (lane == 0) out[row] = v + bf3[0];
}

extern "C" void kernel_launch(void* const* d_in, const int* in_sizes, int n_in,
                              void* d_out, int out_size, void* d_ws, size_t ws_size,
                              hipStream_t stream)
{
    const int*   inputs       = (const int*)  d_in[0];
    const float* node_feature = (const float*)d_in[1];
    const float* edge_feature = (const float*)d_in[2];
    const int*   edge_src     = (const int*)  d_in[3];
    const int*   edge_dst     = (const int*)  d_in[4];
    const int*   edge_rel     = (const int*)  d_in[5];
    const float* We1 = (const float*)d_in[6];
    const float* be1 = (const float*)d_in[7];
    const float* Wl1 = (const float*)d_in[8];
    const float* bl1 = (const float*)d_in[9];
    const float* Ws1 = (const float*)d_in[10];
    const float* bs1 = (const float*)d_in[11];
    const float* We2 = (const float*)d_in[12];
    const float* be2 = (const float*)d_in[13];
    const float* Wl2 = (const float*)d_in[14];
    const float* bl2 = (const float*)d_in[15];
    const float* Ws2 = (const float*)d_in[16];
    const float* bs2 = (const float*)d_in[17];
    const float* Wc1 = (const float*)d_in[18];
    const float* bc1 = (const float*)d_in[19];
    const float* Wc2 = (const float*)d_in[20];
    const float* bc2 = (const float*)d_in[21];
    const float* Wf1 = (const float*)d_in[22];
    const float* bf1 = (const float*)d_in[23];
    const float* Wf2 = (const float*)d_in[24];
    const float* bf2 = (const float*)d_in[25];
    const float* Wf3 = (const float*)d_in[26];
    const float* bf3 = (const float*)d_in[27];
    float* out = (float*)d_out;

    // ---- workspace layout (256B aligned chunks) ----
    char* p = (char*)d_ws;
    auto alloc = [&](size_t bytes) { char* r = p; p += (bytes + 255) & ~(size_t)255; return r; };
    int* hist     = (int*)alloc(NSEG * 4);
    int* offs     = (int*)alloc(NSEG * 4);
    int* cursor   = (int*)alloc(NSEG * 4);
    int* csr_src  = (int*)alloc(N_EDGES * 4);
    int* csr_eid  = (int*)alloc(N_EDGES * 4);
    int* bsums    = (int*)alloc(128 * 4);
    bf16_t* A1    = (bf16_t*)alloc((size_t)N_NODES * K1 * 2);
    bf16_t* A2    = (bf16_t*)alloc((size_t)N_NODES * K2 * 2);
    bf16_t* xb    = (bf16_t*)alloc((size_t)N_NODES * 256 * 2);
    bf16_t* Pbuf  = (bf16_t*)alloc((size_t)N_NODES * HID * 2);
    float*  h2base= (float*)alloc((size_t)N_NODES * 128 * 4);
    bf16_t* h2    = (bf16_t*)alloc((size_t)N_NODES * 128 * 2);
    bf16_t* W1cat = (bf16_t*)alloc((size_t)512 * K1 * 2);
    bf16_t* W2cat = (bf16_t*)alloc((size_t)128 * K2 * 2);
    bf16_t* W2p   = (bf16_t*)alloc((size_t)512 * 512 * 2);
    bf16_t* Wc1b  = (bf16_t*)alloc(256 * 64 * 2);
    bf16_t* Wc2b  = (bf16_t*)alloc(128 * 256 * 2);
    bf16_t* Wf1b  = (bf16_t*)alloc(128 * 384 * 2);
    bf16_t* Wf2b  = (bf16_t*)alloc(64 * 128 * 2);
    float*  bias12= (float*)alloc(512 * 4);
    float*  bias22= (float*)alloc(128 * 4);
    bf16_t* ef_g  = (bf16_t*)alloc((size_t)BATCH * 64 * 2);
    bf16_t* u3    = (bf16_t*)alloc((size_t)BATCH * 256 * 2);
    bf16_t* xcat  = (bf16_t*)alloc((size_t)BATCH * 384 * 2);
    bf16_t* f1    = (bf16_t*)alloc((size_t)BATCH * 128 * 2);
    bf16_t* f2    = (bf16_t*)alloc((size_t)BATCH * 64 * 2);

    // ---- CSR build ----
    hipMemsetAsync(hist, 0, NSEG * 4, stream);
    hipMemsetAsync(cursor, 0, NSEG * 4, stream);
    hist_kernel<<<(N_EDGES + 255) / 256, 256, 0, stream>>>(edge_dst, edge_rel, hist);
    int nscan = (NSEG + SCAN_B - 1) / SCAN_B;
    scan1<<<nscan, 256, 0, stream>>>(hist, offs, bsums, NSEG);
    scan2<<<1, 64, 0, stream>>>(bsums, nscan);
    scan3<<<nscan, 256, 0, stream>>>(offs, bsums, NSEG);
    csr_fill<<<(N_EDGES + 255) / 256, 256, 0, stream>>>(edge_dst, edge_rel, edge_src,
                                                        offs, cursor, csr_src, csr_eid);

    // ---- weight prep + converts ----
    prep_w1cat<<<512, 256, 0, stream>>>(Wl1, We1, Ws1, be1, W1cat);
    prep_w2cat<<<128, 256, 0, stream>>>(Wl2, We2, Ws2, be2, W2cat);
    prep_w2p<<<(512 * 512) / 256, 256, 0, stream>>>(Wl2, W2p);
    f2bf4_k<<<(256 * 64 / 4 + 255) / 256, 256, 0, stream>>>(Wc1, Wc1b, 256 * 64 / 4);
    f2bf4_k<<<(128 * 256 / 4 + 255) / 256, 256, 0, stream>>>(Wc2, Wc2b, 128 * 256 / 4);
    f2bf4_k<<<(128 * 384 / 4 + 255) / 256, 256, 0, stream>>>(Wf1, Wf1b, 128 * 384 / 4);
    f2bf4_k<<<(64 * 128 / 4 + 255) / 256, 256, 0, stream>>>(Wf2, Wf2b, 64 * 128 / 4);
    addbias_k<<<2, 256, 0, stream>>>(bl1, bs1, bias12, 512);
    addbias_k<<<1, 256, 0, stream>>>(bl2, bs2, bias22, 128);
    xconv_k<<<(N_NODES * 64 + 255) / 256, 256, 0, stream>>>(node_feature, A1, xb);

    // ---- layer 1 ----
    agg1<<<N_NODES, 256, 0, stream>>>(edge_feature, xb, csr_src, csr_eid, offs, hist, A1, A2);
    {   // h1 = relu(A1 @ W1cat^T + bias12) -> A2 cols 256..767
        int nrow = (N_NODES + 127) / 128, ncol = HID / 128;
        gemm_bf16<1, 0, 1><<<nrow * ncol, 256, 0, stream>>>(A1, K1, W1cat, K1, nullptr, 0, bias12,
                                                            A2 + 256, K2, N_NODES, HID, K1, ncol);
    }

    // ---- layer 2 ----
    {   // P = h1 @ W2p^T
        int nrow = (N_NODES + 127) / 128, ncol = HID / 128;
        gemm_bf16<0, 0, 1><<<nrow * ncol, 256, 0, stream>>>(A2 + 256, K2, W2p, 512, nullptr, 0, nullptr,
                                                            Pbuf, HID, N_NODES, HID, 512, ncol);
    }
    agg2<<<N_NODES, 256, 0, stream>>>(Pbuf, csr_src, offs, hist, h2base);
    {   // h2 = relu(h2base + A2 @ W2cat^T + bias22)
        int nrow = (N_NODES + 127) / 128;
        gemm_bf16<1, 1, 1><<<nrow, 256, 0, stream>>>(A2, K2, W2cat, K2, h2base, 128, bias22,
                                                     h2, 128, N_NODES, 128, K2, 1);
    }

    // ---- head ----
    gather_head<<<BATCH, 256, 0, stream>>>(inputs, h2, edge_feature, xcat, ef_g);
    {   // u3 = relu(ef_g @ Wc1^T + bc1)
        gemm_bf16<1, 0, 1><<<(BATCH / 128) * 2, 256, 0, stream>>>(ef_g, 64, Wc1b, 64, nullptr, 0, bc1,
                                                                  u3, 256, BATCH, 256, 64, 2);
    }
    {   // xcat[:,256:384] = u3 @ Wc2^T + bc2
        gemm_bf16<0, 0, 1><<<BATCH / 128, 256, 0, stream>>>(u3, 256, Wc2b, 256, nullptr, 0, bc2,
                                                            xcat + 256, 384, BATCH, 128, 256, 1);
    }
    {   // f1 = relu(xcat @ Wf1^T + bf1)
        gemm_bf16<1, 0, 1><<<BATCH / 128, 256, 0, stream>>>(xcat, 384, Wf1b, 384, nullptr, 0, bf1,
                                                            f1, 128, BATCH, 128, 384, 1);
    }
    {   // f2 = relu(f1 @ Wf2^T + bf2)
        gemm_bf16<1, 0, 1><<<BATCH / 128, 256, 0, stream>>>(f1, 128, Wf2b, 128, nullptr, 0, bf2,
                                                            f2, 64, BATCH, 64, 128, 1);
    }
    final_matvec<<<BATCH / 4, 256, 0, stream>>>(f2, Wf3, bf3, out, BATCH);
}

// Round 6
// 730.590 us; speedup vs baseline: 22.2246x; 1.0268x over previous
//
#include <hip/hip_runtime.h>
#include <hip/hip_bf16.h>

#define N_NODES 50000
#define N_EDGES 800000
#define NODE_DIM 256
#define EDGE_DIM 64
#define NUM_REL 4
#define HID 512
#define LAST 128
#define BATCH 16384
#define EPS 1e-10f
#define NSEG (N_NODES * NUM_REL)

#define K1 1600   // meanX 1024 | E1 256 | x 256 | f 4 | pad 60
#define K2 832    // E1 256 | h1 512 | f 4 | pad 60

typedef __bf16 bf16_t;
typedef __attribute__((ext_vector_type(8))) __bf16 bf16x8;
typedef __attribute__((ext_vector_type(4))) __bf16 bf16x4;
typedef __attribute__((ext_vector_type(2))) __bf16 bf16x2;
typedef __attribute__((ext_vector_type(4))) float f32x4;

typedef __attribute__((address_space(1))) const unsigned int g_u32;
typedef __attribute__((address_space(3))) unsigned int l_u32;
static __device__ __forceinline__ void gload16(const void* g, void* l) {
    __builtin_amdgcn_global_load_lds((g_u32*)g, (l_u32*)l, 16, 0, 0);
}

// ================= CSR build =================
__global__ __launch_bounds__(256) void hist_kernel(
    const int* __restrict__ edst, const int* __restrict__ erel, int* __restrict__ hist)
{
    int e = blockIdx.x * 256 + threadIdx.x;
    if (e >= N_EDGES) return;
    atomicAdd(&hist[edst[e] * NUM_REL + erel[e]], 1);
}

#define SCAN_B 2048
__global__ __launch_bounds__(256) void scan1(
    const int* __restrict__ in, int* __restrict__ out, int* __restrict__ bsum, int n)
{
    __shared__ int sh[256];
    int base = blockIdx.x * SCAN_B + threadIdx.x * 8;
    int v[8]; int s = 0;
#pragma unroll
    for (int i = 0; i < 8; ++i) {
        int idx = base + i;
        v[i] = s;
        s += (idx < n) ? in[idx] : 0;
    }
    sh[threadIdx.x] = s;
    __syncthreads();
    for (int off = 1; off < 256; off <<= 1) {
        int t = (threadIdx.x >= off) ? sh[threadIdx.x - off] : 0;
        __syncthreads();
        sh[threadIdx.x] += t;
        __syncthreads();
    }
    int texcl = (threadIdx.x == 0) ? 0 : sh[threadIdx.x - 1];
#pragma unroll
    for (int i = 0; i < 8; ++i) {
        int idx = base + i;
        if (idx < n) out[idx] = texcl + v[i];
    }
    if (threadIdx.x == 255) bsum[blockIdx.x] = sh[255];
}

__global__ void scan2(int* bsum, int nb)
{
    if (threadIdx.x == 0 && blockIdx.x == 0) {
        int s = 0;
        for (int i = 0; i < nb; ++i) { int t = bsum[i]; bsum[i] = s; s += t; }
    }
}

__global__ __launch_bounds__(256) void scan3(int* __restrict__ out, const int* __restrict__ bsum, int n)
{
    int idx = blockIdx.x * SCAN_B + threadIdx.x * 8;
    int add = bsum[blockIdx.x];
#pragma unroll
    for (int i = 0; i < 8; ++i)
        if (idx + i < n) out[idx + i] += add;
}

__global__ __launch_bounds__(256) void csr_fill(
    const int* __restrict__ edst, const int* __restrict__ erel, const int* __restrict__ esrc,
    const int* __restrict__ offs, int* __restrict__ cursor,
    int* __restrict__ csr_src, int* __restrict__ csr_eid)
{
    int e = blockIdx.x * 256 + threadIdx.x;
    if (e >= N_EDGES) return;
    int seg = edst[e] * NUM_REL + erel[e];
    int pos = offs[seg] + atomicAdd(&cursor[seg], 1);
    csr_src[pos] = esrc[e];
    csr_eid[pos] = e;
}

// ================= small converts, fused =================
// ranges (in float4 units): Wc1 4096 | Wc2 8192 | Wf1 12288 | Wf2 2048 ; then scalars
__global__ __launch_bounds__(256) void prep_small(
    const float* __restrict__ Wc1, const float* __restrict__ Wc2,
    const float* __restrict__ Wf1, const float* __restrict__ Wf2,
    const float* __restrict__ bl1, const float* __restrict__ bs1,
    const float* __restrict__ bl2, const float* __restrict__ bs2,
    bf16_t* __restrict__ Wc1b, bf16_t* __restrict__ Wc2b,
    bf16_t* __restrict__ Wf1b, bf16_t* __restrict__ Wf2b,
    float* __restrict__ bias12, float* __restrict__ bias22)
{
    int i = blockIdx.x * 256 + threadIdx.x;
    const float* src; bf16_t* dst; int base;
    if (i < 4096)        { src = Wc1; dst = Wc1b; base = 0; }
    else if (i < 12288)  { src = Wc2; dst = Wc2b; base = 4096; }
    else if (i < 24576)  { src = Wf1; dst = Wf1b; base = 12288; }
    else if (i < 26624)  { src = Wf2; dst = Wf2b; base = 24576; }
    else {
        int j = i - 26624;
        if (j < 512) bias12[j] = bl1[j] + bs1[j];
        else if (j < 640) bias22[j - 512] = bl2[j - 512] + bs2[j - 512];
        return;
    }
    int k = i - base;
    float4 v = ((const float4*)src)[k];
    bf16x4 o;
    o[0] = (bf16_t)v.x; o[1] = (bf16_t)v.y; o[2] = (bf16_t)v.z; o[3] = (bf16_t)v.w;
    ((bf16x4*)dst)[k] = o;
}

// x (fp32 [50000,256]) -> A1 cols 1280..1535 (bf16) AND compact xb [50000,256]
__global__ __launch_bounds__(256) void xconv_k(const float* __restrict__ x, bf16_t* __restrict__ A1,
                                               bf16_t* __restrict__ xb)
{
    int i = blockIdx.x * 256 + threadIdx.x;   // over 50000*64
    int n = i >> 6;
    int c4 = i & 63;
    float4 v = ((const float4*)(x + (size_t)n * 256))[c4];
    bf16x4 o;
    o[0] = (bf16_t)v.x; o[1] = (bf16_t)v.y; o[2] = (bf16_t)v.z; o[3] = (bf16_t)v.w;
    *(bf16x4*)(A1 + (size_t)n * K1 + 1280 + c4 * 4) = o;
    *(bf16x4*)(xb + (size_t)n * 256 + c4 * 4) = o;
}

// ================= weight prep =================
__global__ __launch_bounds__(256) void prep_w1cat(
    const float* __restrict__ Wl1, const float* __restrict__ We1,
    const float* __restrict__ Ws1, const float* __restrict__ be1, bf16_t* __restrict__ W1cat)
{
    int j = blockIdx.x;
    int t = threadIdx.x;
    const float* wrow = Wl1 + (size_t)j * 1024;
    bf16_t* out = W1cat + (size_t)j * K1;
    for (int c = t; c < 1024; c += 256) out[c] = (bf16_t)wrow[c];
    {
        int r = t >> 6, e = t & 63;
        float s = 0.f;
        const float* wr = wrow + r * 256;
        for (int c = 0; c < 256; ++c) s += wr[c] * We1[c * 64 + e];
        out[1024 + t] = (bf16_t)s;
    }
    if (t < 256) out[1280 + t] = (bf16_t)Ws1[(size_t)j * 256 + t];
    if (t < 4) {
        float s = 0.f;
        const float* wr = wrow + t * 256;
        for (int c = 0; c < 256; ++c) s += wr[c] * be1[c];
        out[1536 + t] = (bf16_t)s;
    }
    if (t >= 4 && t < 64) out[1536 + t] = (bf16_t)0.f;   // pad to K1=1600
}

__global__ __launch_bounds__(256) void prep_w2cat(
    const float* __restrict__ Wl2, const float* __restrict__ We2,
    const float* __restrict__ Ws2, const float* __restrict__ be2, bf16_t* __restrict__ W2cat)
{
    int j = blockIdx.x;
    int t = threadIdx.x;
    const float* wrow = Wl2 + (size_t)j * 2048;
    bf16_t* out = W2cat + (size_t)j * K2;
    {
        int r = t >> 6, e = t & 63;
        float s = 0.f;
        const float* wr = wrow + r * 512;
        for (int k = 0; k < 512; ++k) s += wr[k] * We2[k * 64 + e];
        out[t] = (bf16_t)s;
    }
    for (int c = t; c < 512; c += 256) out[256 + c] = (bf16_t)Ws2[(size_t)j * 512 + c];
    if (t < 4) {
        float s = 0.f;
        const float* wr = wrow + t * 512;
        for (int k = 0; k < 512; ++k) s += wr[k] * be2[k];
        out[768 + t] = (bf16_t)s;
    }
    if (t >= 4 && t < 64) out[768 + t] = (bf16_t)0.f;    // pad to K2=832
}

__global__ __launch_bounds__(256) void prep_w2p(const float* __restrict__ Wl2, bf16_t* __restrict__ W2p)
{
    int idx = blockIdx.x * 256 + threadIdx.x;    // 512*512
    int row = idx >> 9, k = idx & 511;
    int j = row & 127, r = row >> 7;
    W2p[idx] = (bf16_t)Wl2[(size_t)j * 2048 + r * 512 + k];
}

// ================= aggregation =================
// block = node n; wave = relation r; lanes split in halves: half h handles edge i+h.
// One 16B xb load + one 8B ef load covers TWO edges per iteration; x2 pair unroll.
__global__ __launch_bounds__(256) void agg1(
    const float* __restrict__ ef, const bf16_t* __restrict__ xb,
    const int* __restrict__ csr_src, const int* __restrict__ csr_eid,
    const int* __restrict__ offs, const int* __restrict__ hist,
    bf16_t* __restrict__ A1, bf16_t* __restrict__ A2)
{
    int n = blockIdx.x;
    int w = threadIdx.x >> 6;
    int lane = threadIdx.x & 63;
    int half = lane >> 5;
    int l32 = lane & 31;
    int seg = n * NUM_REL + w;
    int beg = offs[seg], ct = hist[seg];

    float xs[8] = {0.f, 0.f, 0.f, 0.f, 0.f, 0.f, 0.f, 0.f};
    float es0 = 0.f, es1 = 0.f;

    int i = 0;
    for (; i + 4 <= ct; i += 4) {
        int sA = csr_src[beg + i + half];
        int sB = csr_src[beg + i + 2 + half];
        int eA = csr_eid[beg + i + half];
        int eB = csr_eid[beg + i + 2 + half];
        bf16x8 vA = *(const bf16x8*)(xb + (size_t)sA * 256 + l32 * 8);
        bf16x8 vB = *(const bf16x8*)(xb + (size_t)sB * 256 + l32 * 8);
        float2 fA = *(const float2*)(ef + (size_t)eA * 64 + l32 * 2);
        float2 fB = *(const float2*)(ef + (size_t)eB * 64 + l32 * 2);
#pragma unroll
        for (int j = 0; j < 8; ++j) xs[j] += (float)vA[j] + (float)vB[j];
        es0 += fA.x + fB.x;
        es1 += fA.y + fB.y;
    }
    for (; i + 2 <= ct; i += 2) {
        int sA = csr_src[beg + i + half];
        int eA = csr_eid[beg + i + half];
        bf16x8 vA = *(const bf16x8*)(xb + (size_t)sA * 256 + l32 * 8);
        float2 fA = *(const float2*)(ef + (size_t)eA * 64 + l32 * 2);
#pragma unroll
        for (int j = 0; j < 8; ++j) xs[j] += (float)vA[j];
        es0 += fA.x;
        es1 += fA.y;
    }
    if (i < ct && half == 0) {
        int sA = csr_src[beg + i];
        int eA = csr_eid[beg + i];
        bf16x8 vA = *(const bf16x8*)(xb + (size_t)sA * 256 + l32 * 8);
        float2 fA = *(const float2*)(ef + (size_t)eA * 64 + l32 * 2);
#pragma unroll
        for (int j = 0; j < 8; ++j) xs[j] += (float)vA[j];
        es0 += fA.x;
        es1 += fA.y;
    }
    // combine halves
#pragma unroll
    for (int j = 0; j < 8; ++j) xs[j] += __shfl_xor(xs[j], 32);
    es0 += __shfl_xor(es0, 32);
    es1 += __shfl_xor(es1, 32);

    float inv = 1.0f / ((float)ct + EPS);
    if (half == 0) {
        bf16x8 m;
#pragma unroll
        for (int j = 0; j < 8; ++j) m[j] = (bf16_t)(xs[j] * inv);
        *(bf16x8*)(A1 + (size_t)n * K1 + w * 256 + l32 * 8) = m;
        bf16x2 e2;
        e2[0] = (bf16_t)(es0 * inv);
        e2[1] = (bf16_t)(es1 * inv);
        *(bf16x2*)(A1 + (size_t)n * K1 + 1024 + w * 64 + l32 * 2) = e2;
        *(bf16x2*)(A2 + (size_t)n * K2 + w * 64 + l32 * 2) = e2;
    }
    if (lane == 0) {
        bf16_t fv = (bf16_t)((float)ct * inv);
        A1[(size_t)n * K1 + 1536 + w] = fv;
        A2[(size_t)n * K2 + 768 + w] = fv;
    }
    if (w == 3 && lane >= 4) {
        A1[(size_t)n * K1 + 1536 + lane] = (bf16_t)0.f;   // 1540..1599
        A2[(size_t)n * K2 + 768 + lane] = (bf16_t)0.f;    // 772..831
    }
}

// block = node n; wave = relation r; paired-edge lanes; 8B load covers 2 edges.
__global__ __launch_bounds__(256) void agg2(
    const bf16_t* __restrict__ P, const int* __restrict__ csr_src,
    const int* __restrict__ offs, const int* __restrict__ hist,
    float* __restrict__ h2base)
{
    __shared__ float red[4][128];
    int n = blockIdx.x;
    int w = threadIdx.x >> 6;
    int lane = threadIdx.x & 63;
    int half = lane >> 5;
    int l32 = lane & 31;
    int seg = n * NUM_REL + w;
    int beg = offs[seg], ct = hist[seg];

    float s0 = 0.f, s1 = 0.f, s2 = 0.f, s3 = 0.f;
    int i = 0;
    for (; i + 4 <= ct; i += 4) {
        int a = csr_src[beg + i + half];
        int b = csr_src[beg + i + 2 + half];
        bf16x4 va = *(const bf16x4*)(P + (size_t)a * HID + w * 128 + l32 * 4);
        bf16x4 vb = *(const bf16x4*)(P + (size_t)b * HID + w * 128 + l32 * 4);
        s0 += (float)va[0] + (float)vb[0];
        s1 += (float)va[1] + (float)vb[1];
        s2 += (float)va[2] + (float)vb[2];
        s3 += (float)va[3] + (float)vb[3];
    }
    for (; i + 2 <= ct; i += 2) {
        int a = csr_src[beg + i + half];
        bf16x4 va = *(const bf16x4*)(P + (size_t)a * HID + w * 128 + l32 * 4);
        s0 += (float)va[0]; s1 += (float)va[1]; s2 += (float)va[2]; s3 += (float)va[3];
    }
    if (i < ct && half == 0) {
        int a = csr_src[beg + i];
        bf16x4 va = *(const bf16x4*)(P + (size_t)a * HID + w * 128 + l32 * 4);
        s0 += (float)va[0]; s1 += (float)va[1]; s2 += (float)va[2]; s3 += (float)va[3];
    }
    s0 += __shfl_xor(s0, 32);
    s1 += __shfl_xor(s1, 32);
    s2 += __shfl_xor(s2, 32);
    s3 += __shfl_xor(s3, 32);

    float inv = 1.0f / ((float)ct + EPS);
    if (half == 0) {
        red[w][l32 * 4 + 0] = s0 * inv;
        red[w][l32 * 4 + 1] = s1 * inv;
        red[w][l32 * 4 + 2] = s2 * inv;
        red[w][l32 * 4 + 3] = s3 * inv;
    }
    __syncthreads();
    int t = threadIdx.x;
    if (t < 128)
        h2base[(size_t)n * 128 + t] = red[0][t] + red[1][t] + red[2][t] + red[3][t];
}

// ================= bf16 MFMA GEMM =================
// C = act(A[M,K]@W[N,K]^T + bias [+ Cin]); 128x128 tile, BK=64, 4 waves.
// LDS rows are 128B, chunk slot = global_kchunk ^ (row&7): swizzle realized by
// permuting the per-lane GLOBAL source (linear gload_lds dest) + XOR on read.
// K must be a multiple of 64. Grid is 1D, column-fastest (col = bid % ncol).
template<int RELU, int ACC, int OUTBF>
__global__ __launch_bounds__(256) void gemm_bf16(
    const bf16_t* __restrict__ A, int lda,
    const bf16_t* __restrict__ W, int ldw,
    const float* __restrict__ Cin, int ldcin,
    const float* __restrict__ bias,
    void* __restrict__ Cout, int ldc,
    int M, int N, int K, int ncol)
{
    __shared__ char smem[32768];
    char* As = smem;            // [128 rows][8 slots][16B]
    char* Bs = smem + 16384;
    const int tid = threadIdx.x;
    const int row0 = (blockIdx.x / ncol) * 128;
    const int col0 = (blockIdx.x % ncol) * 128;
    const int lane = tid & 63, wv = tid >> 6;

    // staging: wave wv stages 8-row groups q = wv*4+s (s=0..3) of both A and B.
    const int rsub = lane >> 3;
    const int gchunk = (lane & 7) ^ rsub;
    const bf16_t* pa[4]; const bf16_t* pb[4];
    char* la[4]; char* lb[4];
#pragma unroll
    for (int s = 0; s < 4; ++s) {
        int q = wv * 4 + s;
        int ar = row0 + q * 8 + rsub; if (ar >= M) ar = M - 1;
        int br = col0 + q * 8 + rsub; if (br >= N) br = N - 1;
        pa[s] = A + (size_t)ar * lda + gchunk * 8;
        pb[s] = W + (size_t)br * ldw + gchunk * 8;
        la[s] = As + q * 1024;
        lb[s] = Bs + q * 1024;
    }

    const int wm = wv >> 1, wn = wv & 1;
    const int r16 = lane & 15, kch = lane >> 4;
    const int sw = r16 & 7;

    f32x4 zero = {0.f, 0.f, 0.f, 0.f};
    f32x4 acc[4][4];
#pragma unroll
    for (int i = 0; i < 4; ++i)
#pragma unroll
        for (int j = 0; j < 4; ++j) acc[i][j] = zero;

    for (int k0 = 0; k0 < K; k0 += 64) {
#pragma unroll
        for (int s = 0; s < 4; ++s) {
            gload16(pa[s] + k0, la[s]);
            gload16(pb[s] + k0, lb[s]);
        }
        __syncthreads();
#pragma unroll
        for (int t = 0; t < 2; ++t) {
            const int slot = ((t * 4 + kch) ^ sw) << 4;
            bf16x8 af[4], bfm[4];
#pragma unroll
            for (int i = 0; i < 4; ++i)
                af[i] = *(const bf16x8*)(As + (wm * 64 + i * 16 + r16) * 128 + slot);
#pragma unroll
            for (int j = 0; j < 4; ++j)
                bfm[j] = *(const bf16x8*)(Bs + (wn * 64 + j * 16 + r16) * 128 + slot);
#pragma unroll
            for (int i = 0; i < 4; ++i)
#pragma unroll
                for (int j = 0; j < 4; ++j)
                    acc[i][j] = __builtin_amdgcn_mfma_f32_16x16x32_bf16(af[i], bfm[j], acc[i][j], 0, 0, 0);
        }
        __syncthreads();
    }

    const int crow0 = row0 + wm * 64;
#pragma unroll
    for (int i = 0; i < 4; ++i) {
#pragma unroll
        for (int j = 0; j < 4; ++j) {
            int col = col0 + wn * 64 + j * 16 + r16;
            if (col >= N) continue;
            float bv = bias ? bias[col] : 0.f;
#pragma unroll
            for (int q = 0; q < 4; ++q) {
                int row = crow0 + i * 16 + kch * 4 + q;
                if (row >= M) continue;
                float v = acc[i][j][q] + bv;
                if (ACC) v += Cin[(size_t)row * ldcin + col];
                if (RELU) v = fmaxf(v, 0.f);
                if (OUTBF) ((bf16_t*)Cout)[(size_t)row * ldc + col] = (bf16_t)v;
                else       ((float*)Cout)[(size_t)row * ldc + col] = v;
            }
        }
    }
}

// ================= head =================
__global__ __launch_bounds__(256) void gather_head(
    const int* __restrict__ inputs, const bf16_t* __restrict__ h2,
    const float* __restrict__ ef, bf16_t* __restrict__ xcat, bf16_t* __restrict__ ef_g)
{
    int i = blockIdx.x;
    int t = threadIdx.x;
    int d1 = inputs[i * 3 + 0];
    int d2 = inputs[i * 3 + 1];
    int ctx = inputs[i * 3 + 2];
    if (t < 128) {
        xcat[(size_t)i * 384 + t] = h2[(size_t)d1 * LAST + t];
    } else {
        int c = t - 128;
        xcat[(size_t)i * 384 + 128 + c] = h2[(size_t)d2 * LAST + c];
    }
    if (t < 64) ef_g[(size_t)i * 64 + t] = (bf16_t)ef[(size_t)ctx * EDGE_DIM + t];
}

__global__ __launch_bounds__(256) void final_matvec(
    const bf16_t* __restrict__ f2, const float* __restrict__ Wf3,
    const float* __restrict__ bf3, float* __restrict__ out, int M)
{
    int row = blockIdx.x * 4 + (threadIdx.x >> 6);
    int lane = threadIdx.x & 63;
    if (row >= M) return;
    float v = (float)f2[(size_t)row * 64 + lane] * Wf3[lane];
#pragma unroll
    for (int off = 32; off > 0; off >>= 1) v += __shfl_down(v, off);
    if (lane == 0) out[row] = v + bf3[0];
}

extern "C" void kernel_launch(void* const* d_in, const int* in_sizes, int n_in,
                              void* d_out, int out_size, void* d_ws, size_t ws_size,
                              hipStream_t stream)
{
    const int*   inputs       = (const int*)  d_in[0];
    const float* node_feature = (const float*)d_in[1];
    const float* edge_feature = (const float*)d_in[2];
    const int*   edge_src     = (const int*)  d_in[3];
    const int*   edge_dst     = (const int*)  d_in[4];
    const int*   edge_rel     = (const int*)  d_in[5];
    const float* We1 = (const float*)d_in[6];
    const float* be1 = (const float*)d_in[7];
    const float* Wl1 = (const float*)d_in[8];
    const float* bl1 = (const float*)d_in[9];
    const float* Ws1 = (const float*)d_in[10];
    const float* bs1 = (const float*)d_in[11];
    const float* We2 = (const float*)d_in[12];
    const float* be2 = (const float*)d_in[13];
    const float* Wl2 = (const float*)d_in[14];
    const float* bl2 = (const float*)d_in[15];
    const float* Ws2 = (const float*)d_in[16];
    const float* bs2 = (const float*)d_in[17];
    const float* Wc1 = (const float*)d_in[18];
    const float* bc1 = (const float*)d_in[19];
    const float* Wc2 = (const float*)d_in[20];
    const float* bc2 = (const float*)d_in[21];
    const float* Wf1 = (const float*)d_in[22];
    const float* bf1 = (const float*)d_in[23];
    const float* Wf2 = (const float*)d_in[24];
    const float* bf2 = (const float*)d_in[25];
    const float* Wf3 = (const float*)d_in[26];
    const float* bf3 = (const float*)d_in[27];
    float* out = (float*)d_out;

    // ---- workspace layout (256B aligned chunks) ----
    char* p = (char*)d_ws;
    auto alloc = [&](size_t bytes) { char* r = p; p += (bytes + 255) & ~(size_t)255; return r; };
    int* hist     = (int*)alloc(NSEG * 4);
    int* offs     = (int*)alloc(NSEG * 4);
    int* cursor   = (int*)alloc(NSEG * 4);
    int* csr_src  = (int*)alloc(N_EDGES * 4);
    int* csr_eid  = (int*)alloc(N_EDGES * 4);
    int* bsums    = (int*)alloc(128 * 4);
    bf16_t* A1    = (bf16_t*)alloc((size_t)N_NODES * K1 * 2);
    bf16_t* A2    = (bf16_t*)alloc((size_t)N_NODES * K2 * 2);
    bf16_t* xb    = (bf16_t*)alloc((size_t)N_NODES * 256 * 2);
    bf16_t* Pbuf  = (bf16_t*)alloc((size_t)N_NODES * HID * 2);
    float*  h2base= (float*)alloc((size_t)N_NODES * 128 * 4);
    bf16_t* h2    = (bf16_t*)alloc((size_t)N_NODES * 128 * 2);
    bf16_t* W1cat = (bf16_t*)alloc((size_t)512 * K1 * 2);
    bf16_t* W2cat = (bf16_t*)alloc((size_t)128 * K2 * 2);
    bf16_t* W2p   = (bf16_t*)alloc((size_t)512 * 512 * 2);
    bf16_t* Wc1b  = (bf16_t*)alloc(256 * 64 * 2);
    bf16_t* Wc2b  = (bf16_t*)alloc(128 * 256 * 2);
    bf16_t* Wf1b  = (bf16_t*)alloc(128 * 384 * 2);
    bf16_t* Wf2b  = (bf16_t*)alloc(64 * 128 * 2);
    float*  bias12= (float*)alloc(512 * 4);
    float*  bias22= (float*)alloc(128 * 4);
    bf16_t* ef_g  = (bf16_t*)alloc((size_t)BATCH * 64 * 2);
    bf16_t* u3    = (bf16_t*)alloc((size_t)BATCH * 256 * 2);
    bf16_t* xcat  = (bf16_t*)alloc((size_t)BATCH * 384 * 2);
    bf16_t* f1    = (bf16_t*)alloc((size_t)BATCH * 128 * 2);
    bf16_t* f2    = (bf16_t*)alloc((size_t)BATCH * 64 * 2);

    // ---- CSR build ----
    hipMemsetAsync(hist, 0, NSEG * 4, stream);
    hipMemsetAsync(cursor, 0, NSEG * 4, stream);
    hist_kernel<<<(N_EDGES + 255) / 256, 256, 0, stream>>>(edge_dst, edge_rel, hist);
    int nscan = (NSEG + SCAN_B - 1) / SCAN_B;
    scan1<<<nscan, 256, 0, stream>>>(hist, offs, bsums, NSEG);
    scan2<<<1, 64, 0, stream>>>(bsums, nscan);
    scan3<<<nscan, 256, 0, stream>>>(offs, bsums, NSEG);
    csr_fill<<<(N_EDGES + 255) / 256, 256, 0, stream>>>(edge_dst, edge_rel, edge_src,
                                                        offs, cursor, csr_src, csr_eid);

    // ---- weight prep + converts ----
    prep_w1cat<<<512, 256, 0, stream>>>(Wl1, We1, Ws1, be1, W1cat);
    prep_w2cat<<<128, 256, 0, stream>>>(Wl2, We2, Ws2, be2, W2cat);
    prep_w2p<<<(512 * 512) / 256, 256, 0, stream>>>(Wl2, W2p);
    prep_small<<<(26624 + 640 + 255) / 256, 256, 0, stream>>>(
        Wc1, Wc2, Wf1, Wf2, bl1, bs1, bl2, bs2,
        Wc1b, Wc2b, Wf1b, Wf2b, bias12, bias22);
    xconv_k<<<(N_NODES * 64 + 255) / 256, 256, 0, stream>>>(node_feature, A1, xb);

    // ---- layer 1 ----
    agg1<<<N_NODES, 256, 0, stream>>>(edge_feature, xb, csr_src, csr_eid, offs, hist, A1, A2);
    {   // h1 = relu(A1 @ W1cat^T + bias12) -> A2 cols 256..767
        int nrow = (N_NODES + 127) / 128, ncol = HID / 128;
        gemm_bf16<1, 0, 1><<<nrow * ncol, 256, 0, stream>>>(A1, K1, W1cat, K1, nullptr, 0, bias12,
                                                            A2 + 256, K2, N_NODES, HID, K1, ncol);
    }

    // ---- layer 2 ----
    {   // P = h1 @ W2p^T
        int nrow = (N_NODES + 127) / 128, ncol = HID / 128;
        gemm_bf16<0, 0, 1><<<nrow * ncol, 256, 0, stream>>>(A2 + 256, K2, W2p, 512, nullptr, 0, nullptr,
                                                            Pbuf, HID, N_NODES, HID, 512, ncol);
    }
    agg2<<<N_NODES, 256, 0, stream>>>(Pbuf, csr_src, offs, hist, h2base);
    {   // h2 = relu(h2base + A2 @ W2cat^T + bias22)
        int nrow = (N_NODES + 127) / 128;
        gemm_bf16<1, 1, 1><<<nrow, 256, 0, stream>>>(A2, K2, W2cat, K2, h2base, 128, bias22,
                                                     h2, 128, N_NODES, 128, K2, 1);
    }

    // ---- head ----
    gather_head<<<BATCH, 256, 0, stream>>>(inputs, h2, edge_feature, xcat, ef_g);
    {   // u3 = relu(ef_g @ Wc1^T + bc1)
        gemm_bf16<1, 0, 1><<<(BATCH / 128) * 2, 256, 0, stream>>>(ef_g, 64, Wc1b, 64, nullptr, 0, bc1,
                                                                  u3, 256, BATCH, 256, 64, 2);
    }
    {   // xcat[:,256:384] = u3 @ Wc2^T + bc2
        gemm_bf16<0, 0, 1><<<BATCH / 128, 256, 0, stream>>>(u3, 256, Wc2b, 256, nullptr, 0, bc2,
                                                            xcat + 256, 384, BATCH, 128, 256, 1);
    }
    {   // f1 = relu(xcat @ Wf1^T + bf1)
        gemm_bf16<1, 0, 1><<<BATCH / 128, 256, 0, stream>>>(xcat, 384, Wf1b, 384, nullptr, 0, bf1,
                                                            f1, 128, BATCH, 128, 384, 1);
    }
    {   // f2 = relu(f1 @ Wf2^T + bf2)
        gemm_bf16<1, 0, 1><<<BATCH / 128, 256, 0, stream>>>(f1, 128, Wf2b, 128, nullptr, 0, bf2,
                                                            f2, 64, BATCH, 64, 128, 1);
    }
    final_matvec<<<BATCH / 4, 256, 0, stream>>>(f2, Wf3, bf3, out, BATCH);
}